// Round 17
// baseline (542.492 us; speedup 1.0000x reference)
//
#include <hip/hip_runtime.h>
#include <math.h>

typedef unsigned int u32;
typedef unsigned long long u64;

#define BATCH 2
#define CH 128
#define NPTS 8192
#define KNB 16
#define GRP 8
#define EPSN 1e-5f

// ---- workspace layout (bytes), total ~10.8 MB ----
#define WS_A     0           // 8*128 f32   A' = s_g * (we_w1 @ pe_w2)
#define WS_PW1   4096        // 128 float4  folded pe_w1 + pe_bn (sx,sy,sz,bias)
#define WS_WE2   6144        // 64 f32      we_w2
#define WS_PTS   8192        // 16384 float4 {x,y,z,|p|^2}
#define WS_EQ    270336      // B*N*8 f32   t_g - s_g*eq
#define WS_EK    794624      // B*N*8 f32   s_g*ek
#define WS_IDX   1318912     // B*N*16 int
#define WS_VFT   2367488     // B*N*128 f32 v transposed (point-major)

__device__ __forceinline__ float d2f(float4 a, float4 b){
  #pragma clang fp contract(off)
  float dot = a.x*b.x + a.y*b.y + a.z*b.z;
  return (a.w + b.w) - 2.0f*dot;
}
__device__ __forceinline__ u64 shfl_xor_u64(u64 v, int m){
  int lo = __shfl_xor((int)(u32)v, m);
  int hi = __shfl_xor((int)(u32)(v >> 32), m);
  return (((u64)(u32)hi) << 32) | (u32)lo;
}
__device__ __forceinline__ int mbcnt64(u64 bm){
  return (int)__builtin_amdgcn_mbcnt_hi((u32)(bm >> 32),
          __builtin_amdgcn_mbcnt_lo((u32)(bm & 0xFFFFFFFFull), 0u));
}
__device__ __forceinline__ u32 mono32(float d2){
  u32 db = __float_as_uint(d2);
  return (db & 0x80000000u) ? ~db : (db | 0x80000000u);  // monotone float->uint
}

// ---------------- K0: tiny precompute ----------------
__global__ __launch_bounds__(256) void k0_precomp(
    const float* we_w1, const float* pe_w2, const float* pe_w1,
    const float* we_g, const float* we_v,
    const float* pe_g, const float* pe_b, const float* pe_m, const float* pe_v,
    const float* we_w2, float* wsA, float4* wsPW1, float* wsWE2){
  int t = threadIdx.x;
  for (int i = t; i < 1024; i += 256){
    int g = i >> 7, h = i & 127;
    float s = 0.f;
    for (int c = 0; c < 128; ++c) s = fmaf(we_w1[g*128+c], pe_w2[c*128+h], s);
    float sg = we_g[g] / sqrtf(we_v[g] + EPSN);
    wsA[i] = s * sg;
  }
  if (t < 128){
    float s = pe_g[t] / sqrtf(pe_v[t] + EPSN);
    float bb = pe_b[t] - pe_m[t] * s;
    wsPW1[t] = make_float4(s*pe_w1[t*3+0], s*pe_w1[t*3+1], s*pe_w1[t*3+2], bb);
  }
  if (t < 64) wsWE2[t] = we_w2[t];
}

// ---------------- K1: points + squared norms ----------------
__global__ __launch_bounds__(256) void k1_pts(const float* xyz, float4* pts){
  int id = blockIdx.x*256 + threadIdx.x;
  if (id >= BATCH*NPTS) return;
  int b = id >> 13, n = id & (NPTS-1);
  float x = xyz[(b*3+0)*NPTS + n];
  float y = xyz[(b*3+1)*NPTS + n];
  float z = xyz[(b*3+2)*NPTS + n];
  float sq;
  {
    #pragma clang fp contract(off)
    sq = (x*x + y*y) + z*z;
  }
  pts[id] = make_float4(x, y, z, sq);
}

// ---------------- K23: fused projections (k2 role) + exact KNN (k3 role) ----------------
// Verbatim round-16 kernel (verified): roles interleaved 3:4 per 7-block group.
#define K2PTS 32
#define QW   2     // queries per k3 wave-unit
#define CAPQ 288   // candidate slots per query
#define K23_LDS 18432
__global__ __launch_bounds__(256) void k23_fused(
    const float* x, const float* wq, const float* wk, const float* wv,
    const float* bnq_g, const float* bnq_b, const float* bnq_m, const float* bnq_v,
    const float* bnk_g, const float* bnk_b, const float* bnk_m, const float* bnk_v,
    const float* we_w1,
    const float* we_g, const float* we_b, const float* we_m, const float* we_v,
    float* eqT, float* ekT, float* vfT,
    const float4* pts, int* idxout){
  extern __shared__ __align__(16) char smRaw[];
  int t = threadIdx.x;
  int grp = blockIdx.x / 7, rem = blockIdx.x % 7;

  if (rem < 3){
    // ================= k2 role =================
    float (*qk2)[129] = (float(*)[129])smRaw;            // 16512 B
    float* bnS = (float*)(smRaw + 16512);                // 512 B
    float* bnB = (float*)(smRaw + 17024);                // 512 B
    int bid2 = grp*3 + rem;                              // 0..1535
    int mat = bid2 % 3;
    int tmp = bid2 / 3;
    int b   = tmp / (NPTS/K2PTS);
    int n0  = (tmp % (NPTS/K2PTS)) * K2PTS;
    int p = t & 31, og = t >> 5;
    const float* xp = x + (size_t)b*CH*NPTS + n0 + p;
    const float* W = (mat == 0) ? wq : ((mat == 1) ? wk : wv);
    if (mat < 2 && t < 128){
      const float* g_ = mat==0 ? bnq_g : bnk_g;
      const float* b_ = mat==0 ? bnq_b : bnk_b;
      const float* m_ = mat==0 ? bnq_m : bnk_m;
      const float* v_ = mat==0 ? bnq_v : bnk_v;
      float s = g_[t] / sqrtf(v_[t] + EPSN);
      bnS[t] = s;
      bnB[t] = b_[t] - m_[t] * s;
    }
    __syncthreads();
    float acc[16];
    #pragma unroll
    for (int ii = 0; ii < 16; ++ii) acc[ii] = 0.f;
    for (int dd = 0; dd < 32; ++dd){
      float x0 = xp[(size_t)(4*dd+0)*NPTS];
      float x1 = xp[(size_t)(4*dd+1)*NPTS];
      float x2 = xp[(size_t)(4*dd+2)*NPTS];
      float x3 = xp[(size_t)(4*dd+3)*NPTS];
      #pragma unroll
      for (int ii = 0; ii < 16; ++ii){
        int o = og*16 + ii;
        float4 wu = *(const float4*)&W[o*128 + 4*dd];
        acc[ii] = fmaf(wu.x, x0, acc[ii]);
        acc[ii] = fmaf(wu.y, x1, acc[ii]);
        acc[ii] = fmaf(wu.z, x2, acc[ii]);
        acc[ii] = fmaf(wu.w, x3, acc[ii]);
      }
    }
    #pragma unroll
    for (int ii = 0; ii < 16; ++ii){
      int o = og*16 + ii;
      float v = acc[ii];
      if (mat < 2) v = fmaxf(fmaf(bnS[o], v, bnB[o]), 0.f);
      qk2[p][o] = v;
    }
    __syncthreads();
    if (mat < 2){
      int g = t >> 5, pp = t & 31;
      float sg = we_g[g] / sqrtf(we_v[g] + EPSN);
      float tg = we_b[g] - we_m[g] * sg;
      float s = 0.f;
      for (int c4 = 0; c4 < 32; ++c4){
        float4 wv4 = *(const float4*)&we_w1[g*128 + 4*c4];
        float4 qv4 = *(const float4*)&qk2[pp][4*c4];
        s = fmaf(wv4.x, qv4.x, s);
        s = fmaf(wv4.y, qv4.y, s);
        s = fmaf(wv4.z, qv4.z, s);
        s = fmaf(wv4.w, qv4.w, s);
      }
      float val = (mat == 0) ? (tg - sg*s) : (sg*s);
      float* dst = (mat == 0) ? eqT : ekT;
      dst[(b*NPTS + n0 + pp)*8 + g] = val;
    } else {
      #pragma unroll
      for (int i = 0; i < 4; ++i){
        int f = t + 256*i;
        int pp = f >> 5, c4 = (f & 31)*4;
        float4 v = *(const float4*)&qk2[pp][c4];
        *(float4*)&vfT[((size_t)b*NPTS + n0 + pp)*CH + c4] = v;
      }
    }
    return;
  }

  // ================= k3 role (4 wave-units/block) =================
  int wv3 = t >> 6, lane = t & 63;
  u64 (*smBuf)[CAPQ] = (u64(*)[CAPQ])(smRaw + wv3*(QW*CAPQ*8));  // 4608 B/wave
  int unit = (grp*4 + (rem - 3))*4 + wv3;                 // 0..8191
  int b  = unit / (NPTS/QW);
  int q0 = (unit % (NPTS/QW)) * QW;
  const float4* P = pts + b*NPTS;

  #pragma unroll
  for (int s = 0; s < QW*CAPQ/64; ++s){
    int f = s*64 + lane;
    smBuf[f / CAPQ][f % CAPQ] = ~0ull;
  }

  float4 qp[QW];
  #pragma unroll
  for (int i = 0; i < QW; ++i) qp[i] = P[q0 + i];

  float T[QW];
  {
    float v0 = 3.402823466e38f, v1 = 3.402823466e38f;
    #pragma unroll
    for (int j = 0; j < 16; ++j){
      float4 c = P[lane + 64*j];
      v0 = fminf(v0, d2f(qp[0], c));
      v1 = fminf(v1, d2f(qp[1], c));
    }
    float t0 = v0, t1 = v1;
    #pragma unroll
    for (int r = 0; r < 16; ++r){
      float m0 = v0, m1 = v1;
      #pragma unroll
      for (int msk = 1; msk <= 32; msk <<= 1){
        m0 = fminf(m0, __shfl_xor(m0, msk));
        m1 = fminf(m1, __shfl_xor(m1, msk));
      }
      if (v0 == m0) v0 = 3.402823466e38f;
      if (v1 == m1) v1 = 3.402823466e38f;
      t0 = m0; t1 = m1;
    }
    T[0] = t0; T[1] = t1;
  }

  float Tlo[QW], Thi[QW]; int cnt[QW];
  #pragma unroll
  for (int i = 0; i < QW; ++i){ Tlo[i] = -3.0e38f; Thi[i] = 3.0e38f; cnt[i] = 0; }
  auto step = [&](float4 c, u32 m, int i){
    float d2 = d2f(qp[i], c);
    bool pred = d2 <= T[i];
    u64 bm = __ballot(pred);
    if (bm){
      int cc = __popcll(bm);
      if (pred && cnt[i] + cc <= CAPQ){
        int pos = cnt[i] + mbcnt64(bm);
        smBuf[i][pos] = (((u64)mono32(d2)) << 32) | m;
      }
      cnt[i] += cc;
    }
  };
  bool anybad = true;
  for (int att = 0; att < 16 && anybad; ++att){
    #pragma unroll
    for (int i = 0; i < QW; ++i) cnt[i] = 0;
    float4 c0 = P[lane], c1 = P[64 + lane], c2 = P[128 + lane], c3 = P[192 + lane];
    for (int base = 0; base < NPTS; base += 256){
      float4 e0 = c0, e1 = c1, e2 = c2, e3 = c3;
      int nb = base + 256;
      if (nb < NPTS){
        c0 = P[nb       + lane];
        c1 = P[nb +  64 + lane];
        c2 = P[nb + 128 + lane];
        c3 = P[nb + 192 + lane];
      }
      #pragma unroll
      for (int i = 0; i < QW; ++i){
        step(e0, (u32)(base       + lane), i);
        step(e1, (u32)(base +  64 + lane), i);
        step(e2, (u32)(base + 128 + lane), i);
        step(e3, (u32)(base + 192 + lane), i);
      }
    }
    anybad = false;
    #pragma unroll
    for (int i = 0; i < QW; ++i){
      if (cnt[i] > CAPQ){
        Thi[i] = T[i];
        T[i] = (Tlo[i] > -3.0e38f) ? 0.5f*(Tlo[i] + Thi[i])
                                   : ((T[i] > 0.f) ? T[i]*0.5f : T[i]*2.0f - 1.0f);
        anybad = true;
      } else if (cnt[i] < 16){
        Tlo[i] = T[i];
        T[i] = 0.5f*(Tlo[i] + Thi[i]);
        anybad = true;
      }
    }
  }

  {
    int cq0 = cnt[0] < CAPQ ? cnt[0] : CAPQ;
    int cq1 = cnt[1] < CAPQ ? cnt[1] : CAPQ;
    u64 a0, a1, a2, a3, a4, b0, b1, b2, b3, b4;
    a0 = (lane       < cq0) ? smBuf[0][lane      ] : ~0ull;
    a1 = (lane +  64 < cq0) ? smBuf[0][lane +  64] : ~0ull;
    a2 = (lane + 128 < cq0) ? smBuf[0][lane + 128] : ~0ull;
    a3 = (lane + 192 < cq0) ? smBuf[0][lane + 192] : ~0ull;
    a4 = (lane + 256 < cq0) ? smBuf[0][lane + 256] : ~0ull;
    b0 = (lane       < cq1) ? smBuf[1][lane      ] : ~0ull;
    b1 = (lane +  64 < cq1) ? smBuf[1][lane +  64] : ~0ull;
    b2 = (lane + 128 < cq1) ? smBuf[1][lane + 128] : ~0ull;
    b3 = (lane + 192 < cq1) ? smBuf[1][lane + 192] : ~0ull;
    b4 = (lane + 256 < cq1) ? smBuf[1][lane + 256] : ~0ull;
    #define CE_(x,y) { if (y < x){ u64 tm_ = x; x = y; y = tm_; } }
    CE_(a0,a1) CE_(a1,a2) CE_(a2,a3) CE_(a3,a4)
    CE_(a0,a1) CE_(a1,a2) CE_(a2,a3)
    CE_(a0,a1) CE_(a1,a2)
    CE_(a0,a1)
    CE_(b0,b1) CE_(b1,b2) CE_(b2,b3) CE_(b3,b4)
    CE_(b0,b1) CE_(b1,b2) CE_(b2,b3)
    CE_(b0,b1) CE_(b1,b2)
    CE_(b0,b1)
    #undef CE_
    int nq0 = q0, nq1 = q0 + 1;
    #pragma unroll
    for (int r = 0; r < 16; ++r){
      u64 g0 = a0, g1 = b0;
      #pragma unroll
      for (int msk = 1; msk <= 32; msk <<= 1){
        u64 o0 = shfl_xor_u64(g0, msk);
        u64 o1 = shfl_xor_u64(g1, msk);
        g0 = (o0 < g0) ? o0 : g0;
        g1 = (o1 < g1) ? o1 : g1;
      }
      if (a0 == g0){ a0 = a1; a1 = a2; a2 = a3; a3 = a4; a4 = ~0ull; }
      if (b0 == g1){ b0 = b1; b1 = b2; b2 = b3; b3 = b4; b4 = ~0ull; }
      if (lane == 0){
        idxout[(b*NPTS + nq0)*16 + r] = (g0 == ~0ull) ? nq0 : (int)(g0 & (u32)(NPTS-1));
        idxout[(b*NPTS + nq1)*16 + r] = (g1 == ~0ull) ? nq1 : (int)(g1 & (u32)(NPTS-1));
      }
    }
  }
}

// ---------------- K4: fused attention, 8 points/block ----------------
// Each wave handles 2 points sequentially in wave-local phases A+C (no extra
// barriers); phases D/E amortize the pe_w2 (64 KB) and wo (64 KB) streams over
// 8 points instead of 4 -> weight L2 traffic halves (536 -> 268 MB total).
#define H2S 136
#define K4P 8
__global__ __launch_bounds__(256, 3) void k4_attn(
    const float4* pts, const float* eqT, const float* ekT, const int* idxw,
    const float* vfT, const float* wsA, const float4* wsPW1, const float* wsWE2,
    const float* pe_w2, const float* wo,
    const float* bno_g, const float* bno_b, const float* bno_m, const float* bno_v,
    float* out){
  __shared__ __align__(16) float4 smW1[128];        // 2 KB
  __shared__ __align__(16) float4 smP[K4P][16];     // 2 KB  r-vectors
  __shared__ int   smJ[K4P][16];                    // 512 B neighbor indices
  __shared__ float smw[K4P][16][8];                 // 4 KB  weights [k][g]
  __shared__ __align__(16) float smH[K4P][8][H2S];  // 34.8 KB
  __shared__ __align__(16) float smOutv[K4P][128];  // 4 KB
  int t = threadIdx.x;
  int wv = t >> 6, lane = t & 63;
  int b  = blockIdx.x >> 10;          // NPTS/8 = 1024 blocks per batch
  int n0 = (blockIdx.x & 1023) * 8;
  if (t < 128) smW1[t] = wsPW1[t];
  __syncthreads();

  int k = lane >> 2, q = lane & 3;

  for (int r = 0; r < 2; ++r){
    int pl = wv + 4*r;
    int n = n0 + pl;
    int gq = b*NPTS + n;

    // ---- phase A (wave-local): logits + softmax weights ----
    {
      float4 pn  = pts[gq];
      float4 eqa = *(const float4*)&eqT[gq*8];
      float4 eqb = *(const float4*)&eqT[gq*8+4];
      int j = idxw[gq*16 + k] & (NPTS-1);
      int gj = b*NPTS + j;
      float4 pj  = pts[gj];
      float4 eka = *(const float4*)&ekT[gj*8];
      float4 ekb = *(const float4*)&ekT[gj*8+4];
      float rx = pj.x - pn.x, ry = pj.y - pn.y, rz = pj.z - pn.z;
      if (q == 0){
        smP[pl][k] = make_float4(rx, ry, rz, 0.f);
        smJ[pl][k] = j;
      }
      // ee added ONCE after the q-lane reduction
      float ee[8] = {eka.x+eqa.x, eka.y+eqa.y, eka.z+eqa.z, eka.w+eqa.w,
                     ekb.x+eqb.x, ekb.y+eqb.y, ekb.z+eqb.z, ekb.w+eqb.w};
      float lp[8] = {0.f,0.f,0.f,0.f,0.f,0.f,0.f,0.f};
      #pragma unroll
      for (int i = 0; i < 8; ++i){
        int hb = 4*q + 16*i;
        float4 w1;
        w1 = smW1[hb+0]; float hv0 = fmaxf(fmaf(w1.x, rx, fmaf(w1.y, ry, fmaf(w1.z, rz, w1.w))), 0.f);
        w1 = smW1[hb+1]; float hv1 = fmaxf(fmaf(w1.x, rx, fmaf(w1.y, ry, fmaf(w1.z, rz, w1.w))), 0.f);
        w1 = smW1[hb+2]; float hv2 = fmaxf(fmaf(w1.x, rx, fmaf(w1.y, ry, fmaf(w1.z, rz, w1.w))), 0.f);
        w1 = smW1[hb+3]; float hv3 = fmaxf(fmaf(w1.x, rx, fmaf(w1.y, ry, fmaf(w1.z, rz, w1.w))), 0.f);
        #pragma unroll
        for (int g = 0; g < 8; ++g){
          float4 a4 = *(const float4*)&wsA[g*128 + hb];
          lp[g] = fmaf(a4.x, hv0, lp[g]);
          lp[g] = fmaf(a4.y, hv1, lp[g]);
          lp[g] = fmaf(a4.z, hv2, lp[g]);
          lp[g] = fmaf(a4.w, hv3, lp[g]);
        }
      }
      #pragma unroll
      for (int g = 0; g < 8; ++g){
        lp[g] += __shfl_xor(lp[g], 1);
        lp[g] += __shfl_xor(lp[g], 2);
        lp[g] = fmaxf(lp[g] + ee[g], 0.f);
      }
      float lo0 = 0.f, lo1 = 0.f;
      #pragma unroll
      for (int g = 0; g < 8; ++g){
        lo0 = fmaf(wsWE2[(2*q+0)*8 + g], lp[g], lo0);
        lo1 = fmaf(wsWE2[(2*q+1)*8 + g], lp[g], lo1);
      }
      float m0 = lo0, m1 = lo1;
      #pragma unroll
      for (int msk = 4; msk <= 32; msk <<= 1){
        m0 = fmaxf(m0, __shfl_xor(m0, msk));
        m1 = fmaxf(m1, __shfl_xor(m1, msk));
      }
      float e0 = __expf(lo0 - m0), e1 = __expf(lo1 - m1);
      float s0 = e0, s1 = e1;
      #pragma unroll
      for (int msk = 4; msk <= 32; msk <<= 1){
        s0 += __shfl_xor(s0, msk);
        s1 += __shfl_xor(s1, msk);
      }
      smw[pl][k][2*q+0] = e0 / s0;
      smw[pl][k][2*q+1] = e1 / s1;
    }

    // ---- phase C (wave-local): H[g][h] = sum_k w[g,k]*relu(W1[h].r_k) ----
    {
      int g3 = lane >> 3, hh = lane & 7;
      float4 H4[4];
      #pragma unroll
      for (int ii = 0; ii < 4; ++ii) H4[ii] = make_float4(0.f,0.f,0.f,0.f);
      for (int kk = 0; kk < 16; ++kk){
        float4 r4 = smP[pl][kk];
        float wg  = smw[pl][kk][g3];
        #pragma unroll
        for (int ii = 0; ii < 4; ++ii){
          int hb = 4*hh + 32*ii;
          float4 w1;
          w1 = smW1[hb+0]; float hv0 = fmaxf(fmaf(w1.x, r4.x, fmaf(w1.y, r4.y, fmaf(w1.z, r4.z, w1.w))), 0.f);
          w1 = smW1[hb+1]; float hv1 = fmaxf(fmaf(w1.x, r4.x, fmaf(w1.y, r4.y, fmaf(w1.z, r4.z, w1.w))), 0.f);
          w1 = smW1[hb+2]; float hv2 = fmaxf(fmaf(w1.x, r4.x, fmaf(w1.y, r4.y, fmaf(w1.z, r4.z, w1.w))), 0.f);
          w1 = smW1[hb+3]; float hv3 = fmaxf(fmaf(w1.x, r4.x, fmaf(w1.y, r4.y, fmaf(w1.z, r4.z, w1.w))), 0.f);
          H4[ii].x = fmaf(wg, hv0, H4[ii].x);
          H4[ii].y = fmaf(wg, hv1, H4[ii].y);
          H4[ii].z = fmaf(wg, hv2, H4[ii].z);
          H4[ii].w = fmaf(wg, hv3, H4[ii].w);
        }
      }
      #pragma unroll
      for (int ii = 0; ii < 4; ++ii)
        *(float4*)&smH[pl][g3][4*hh + 32*ii] = H4[ii];
    }
  }
  __syncthreads();   // all waves' smH/smw/smJ visible block-wide

  // ---- phase D (block-wide, t<128): outv for all 8 points; pe_w2 rows read once ----
  if (t < 128){
    int c = t, g = c >> 4;
    float acc[K4P];
    #pragma unroll
    for (int pt = 0; pt < K4P; ++pt) acc[pt] = 0.f;
    for (int i = 0; i < 32; ++i){
      float4 pw = *(const float4*)&pe_w2[c*128 + 4*i];
      #pragma unroll
      for (int pt = 0; pt < K4P; ++pt){
        float4 h4 = *(const float4*)&smH[pt][g][4*i];
        acc[pt] = fmaf(pw.x, h4.x, acc[pt]);
        acc[pt] = fmaf(pw.y, h4.y, acc[pt]);
        acc[pt] = fmaf(pw.z, h4.z, acc[pt]);
        acc[pt] = fmaf(pw.w, h4.w, acc[pt]);
      }
    }
    #pragma unroll
    for (int pt = 0; pt < K4P; ++pt){
      #pragma unroll
      for (int kk = 0; kk < 16; ++kk){
        int jj = smJ[pt][kk];
        float wgk = smw[pt][kk][g];
        acc[pt] = fmaf(wgk, vfT[((size_t)b*NPTS + jj)*CH + c], acc[pt]);
      }
      smOutv[pt][c] = acc[pt];
    }
  }
  __syncthreads();

  // ---- phase E (t<128): out[o][n0..n0+7] = bno(wo @ outv), two float4 stores ----
  if (t < 128){
    int o = t;
    float so = bno_g[o] / sqrtf(bno_v[o] + EPSN);
    float bo = bno_b[o] - bno_m[o] * so;
    float fa[K4P];
    #pragma unroll
    for (int pt = 0; pt < K4P; ++pt) fa[pt] = 0.f;
    for (int i = 0; i < 32; ++i){
      float4 pw = *(const float4*)&wo[o*128 + 4*i];
      #pragma unroll
      for (int pt = 0; pt < K4P; ++pt){
        float4 h4 = *(const float4*)&smOutv[pt][4*i];
        fa[pt] = fmaf(pw.x, h4.x, fa[pt]);
        fa[pt] = fmaf(pw.y, h4.y, fa[pt]);
        fa[pt] = fmaf(pw.z, h4.z, fa[pt]);
        fa[pt] = fmaf(pw.w, h4.w, fa[pt]);
      }
    }
    float4 st0, st1;
    st0.x = fmaf(so, fa[0], bo);
    st0.y = fmaf(so, fa[1], bo);
    st0.z = fmaf(so, fa[2], bo);
    st0.w = fmaf(so, fa[3], bo);
    st1.x = fmaf(so, fa[4], bo);
    st1.y = fmaf(so, fa[5], bo);
    st1.z = fmaf(so, fa[6], bo);
    st1.w = fmaf(so, fa[7], bo);
    *(float4*)&out[((size_t)b*CH + o)*NPTS + n0]     = st0;
    *(float4*)&out[((size_t)b*CH + o)*NPTS + n0 + 4] = st1;
  }
}

extern "C" void kernel_launch(void* const* d_in, const int* in_sizes, int n_in,
                              void* d_out, int out_size, void* d_ws, size_t ws_size,
                              hipStream_t stream){
  const float* x     = (const float*)d_in[0];
  const float* xyz   = (const float*)d_in[1];
  const float* wq    = (const float*)d_in[2];
  const float* bnq_g = (const float*)d_in[3];
  const float* bnq_b = (const float*)d_in[4];
  const float* bnq_m = (const float*)d_in[5];
  const float* bnq_v = (const float*)d_in[6];
  const float* wk    = (const float*)d_in[7];
  const float* bnk_g = (const float*)d_in[8];
  const float* bnk_b = (const float*)d_in[9];
  const float* bnk_m = (const float*)d_in[10];
  const float* bnk_v = (const float*)d_in[11];
  const float* wv    = (const float*)d_in[12];
  const float* pe_w1 = (const float*)d_in[13];
  const float* pe_g  = (const float*)d_in[14];
  const float* pe_b  = (const float*)d_in[15];
  const float* pe_m  = (const float*)d_in[16];
  const float* pe_v  = (const float*)d_in[17];
  const float* pe_w2 = (const float*)d_in[18];
  const float* we_w1 = (const float*)d_in[19];
  const float* we_g  = (const float*)d_in[20];
  const float* we_b  = (const float*)d_in[21];
  const float* we_m  = (const float*)d_in[22];
  const float* we_v  = (const float*)d_in[23];
  const float* we_w2 = (const float*)d_in[24];
  const float* wo    = (const float*)d_in[25];
  const float* bno_g = (const float*)d_in[26];
  const float* bno_b = (const float*)d_in[27];
  const float* bno_m = (const float*)d_in[28];
  const float* bno_v = (const float*)d_in[29];

  char* ws = (char*)d_ws;
  float*  wsA   = (float*)(ws + WS_A);
  float4* wsPW1 = (float4*)(ws + WS_PW1);
  float*  wsWE2 = (float*)(ws + WS_WE2);
  float4* pts   = (float4*)(ws + WS_PTS);
  float*  eqT   = (float*)(ws + WS_EQ);
  float*  ekT   = (float*)(ws + WS_EK);
  int*    idxw  = (int*)(ws + WS_IDX);
  float*  vfT   = (float*)(ws + WS_VFT);
  float*  outp  = (float*)d_out;

  k0_precomp<<<dim3(1), dim3(256), 0, stream>>>(we_w1, pe_w2, pe_w1, we_g, we_v,
                                                pe_g, pe_b, pe_m, pe_v, we_w2,
                                                wsA, wsPW1, wsWE2);
  k1_pts<<<dim3(64), dim3(256), 0, stream>>>(xyz, pts);
  // 3584 blocks = 512 groups x (3 k2-role + 4 k3-role)
  k23_fused<<<dim3(3584), dim3(256), K23_LDS, stream>>>(x, wq, wk, wv,
                                               bnq_g, bnq_b, bnq_m, bnq_v,
                                               bnk_g, bnk_b, bnk_m, bnk_v,
                                               we_w1, we_g, we_b, we_m, we_v,
                                               eqT, ekT, vfT, pts, idxw);
  k4_attn<<<dim3(BATCH*(NPTS/K4P)), dim3(256), 0, stream>>>(pts, eqT, ekT, idxw, vfT,
                                                wsA, wsPW1, wsWE2, pe_w2, wo,
                                                bno_g, bno_b, bno_m, bno_v, outp);
}

// Round 18
// 538.609 us; speedup vs baseline: 1.0072x; 1.0072x over previous
//
#include <hip/hip_runtime.h>
#include <math.h>

typedef unsigned int u32;
typedef unsigned long long u64;

#define BATCH 2
#define CH 128
#define NPTS 8192
#define KNB 16
#define GRP 8
#define EPSN 1e-5f

// ---- workspace layout (bytes), total ~10.8 MB ----
#define WS_A     0           // 8*128 f32   A' = s_g * (we_w1 @ pe_w2)
#define WS_PW1   4096        // 128 float4  folded pe_w1 + pe_bn (sx,sy,sz,bias)
#define WS_WE2   6144        // 64 f32      we_w2
#define WS_PTS   8192        // 16384 float4 {x,y,z,|p|^2}
#define WS_EQ    270336      // B*N*8 f32   t_g - s_g*eq
#define WS_EK    794624      // B*N*8 f32   s_g*ek
#define WS_IDX   1318912     // B*N*16 int
#define WS_VFT   2367488     // B*N*128 f32 v transposed (point-major)

__device__ __forceinline__ float d2f(float4 a, float4 b){
  #pragma clang fp contract(off)
  float dot = a.x*b.x + a.y*b.y + a.z*b.z;
  return (a.w + b.w) - 2.0f*dot;
}
__device__ __forceinline__ u64 shfl_xor_u64(u64 v, int m){
  int lo = __shfl_xor((int)(u32)v, m);
  int hi = __shfl_xor((int)(u32)(v >> 32), m);
  return (((u64)(u32)hi) << 32) | (u32)lo;
}
__device__ __forceinline__ int mbcnt64(u64 bm){
  return (int)__builtin_amdgcn_mbcnt_hi((u32)(bm >> 32),
          __builtin_amdgcn_mbcnt_lo((u32)(bm & 0xFFFFFFFFull), 0u));
}
__device__ __forceinline__ u32 mono32(float d2){
  u32 db = __float_as_uint(d2);
  return (db & 0x80000000u) ? ~db : (db | 0x80000000u);  // monotone float->uint
}

// ---------------- K0: tiny precompute ----------------
__global__ __launch_bounds__(256) void k0_precomp(
    const float* we_w1, const float* pe_w2, const float* pe_w1,
    const float* we_g, const float* we_v,
    const float* pe_g, const float* pe_b, const float* pe_m, const float* pe_v,
    const float* we_w2, float* wsA, float4* wsPW1, float* wsWE2){
  int t = threadIdx.x;
  for (int i = t; i < 1024; i += 256){
    int g = i >> 7, h = i & 127;
    float s = 0.f;
    for (int c = 0; c < 128; ++c) s = fmaf(we_w1[g*128+c], pe_w2[c*128+h], s);
    float sg = we_g[g] / sqrtf(we_v[g] + EPSN);
    wsA[i] = s * sg;
  }
  if (t < 128){
    float s = pe_g[t] / sqrtf(pe_v[t] + EPSN);
    float bb = pe_b[t] - pe_m[t] * s;
    wsPW1[t] = make_float4(s*pe_w1[t*3+0], s*pe_w1[t*3+1], s*pe_w1[t*3+2], bb);
  }
  if (t < 64) wsWE2[t] = we_w2[t];
}

// ---------------- K1: points + squared norms ----------------
__global__ __launch_bounds__(256) void k1_pts(const float* xyz, float4* pts){
  int id = blockIdx.x*256 + threadIdx.x;
  if (id >= BATCH*NPTS) return;
  int b = id >> 13, n = id & (NPTS-1);
  float x = xyz[(b*3+0)*NPTS + n];
  float y = xyz[(b*3+1)*NPTS + n];
  float z = xyz[(b*3+2)*NPTS + n];
  float sq;
  {
    #pragma clang fp contract(off)
    sq = (x*x + y*y) + z*z;
  }
  pts[id] = make_float4(x, y, z, sq);
}

// ---------------- K23: fused projections (k2 role) + exact KNN (k3 role) ----------------
// Verbatim round-16 kernel (verified): roles interleaved 3:4 per 7-block group.
#define K2PTS 32
#define QW   2     // queries per k3 wave-unit
#define CAPQ 288   // candidate slots per query
#define K23_LDS 18432
__global__ __launch_bounds__(256) void k23_fused(
    const float* x, const float* wq, const float* wk, const float* wv,
    const float* bnq_g, const float* bnq_b, const float* bnq_m, const float* bnq_v,
    const float* bnk_g, const float* bnk_b, const float* bnk_m, const float* bnk_v,
    const float* we_w1,
    const float* we_g, const float* we_b, const float* we_m, const float* we_v,
    float* eqT, float* ekT, float* vfT,
    const float4* pts, int* idxout){
  extern __shared__ __align__(16) char smRaw[];
  int t = threadIdx.x;
  int grp = blockIdx.x / 7, rem = blockIdx.x % 7;

  if (rem < 3){
    // ================= k2 role =================
    float (*qk2)[129] = (float(*)[129])smRaw;            // 16512 B
    float* bnS = (float*)(smRaw + 16512);                // 512 B
    float* bnB = (float*)(smRaw + 17024);                // 512 B
    int bid2 = grp*3 + rem;                              // 0..1535
    int mat = bid2 % 3;
    int tmp = bid2 / 3;
    int b   = tmp / (NPTS/K2PTS);
    int n0  = (tmp % (NPTS/K2PTS)) * K2PTS;
    int p = t & 31, og = t >> 5;
    const float* xp = x + (size_t)b*CH*NPTS + n0 + p;
    const float* W = (mat == 0) ? wq : ((mat == 1) ? wk : wv);
    if (mat < 2 && t < 128){
      const float* g_ = mat==0 ? bnq_g : bnk_g;
      const float* b_ = mat==0 ? bnq_b : bnk_b;
      const float* m_ = mat==0 ? bnq_m : bnk_m;
      const float* v_ = mat==0 ? bnq_v : bnk_v;
      float s = g_[t] / sqrtf(v_[t] + EPSN);
      bnS[t] = s;
      bnB[t] = b_[t] - m_[t] * s;
    }
    __syncthreads();
    float acc[16];
    #pragma unroll
    for (int ii = 0; ii < 16; ++ii) acc[ii] = 0.f;
    for (int dd = 0; dd < 32; ++dd){
      float x0 = xp[(size_t)(4*dd+0)*NPTS];
      float x1 = xp[(size_t)(4*dd+1)*NPTS];
      float x2 = xp[(size_t)(4*dd+2)*NPTS];
      float x3 = xp[(size_t)(4*dd+3)*NPTS];
      #pragma unroll
      for (int ii = 0; ii < 16; ++ii){
        int o = og*16 + ii;
        float4 wu = *(const float4*)&W[o*128 + 4*dd];
        acc[ii] = fmaf(wu.x, x0, acc[ii]);
        acc[ii] = fmaf(wu.y, x1, acc[ii]);
        acc[ii] = fmaf(wu.z, x2, acc[ii]);
        acc[ii] = fmaf(wu.w, x3, acc[ii]);
      }
    }
    #pragma unroll
    for (int ii = 0; ii < 16; ++ii){
      int o = og*16 + ii;
      float v = acc[ii];
      if (mat < 2) v = fmaxf(fmaf(bnS[o], v, bnB[o]), 0.f);
      qk2[p][o] = v;
    }
    __syncthreads();
    if (mat < 2){
      int g = t >> 5, pp = t & 31;
      float sg = we_g[g] / sqrtf(we_v[g] + EPSN);
      float tg = we_b[g] - we_m[g] * sg;
      float s = 0.f;
      for (int c4 = 0; c4 < 32; ++c4){
        float4 wv4 = *(const float4*)&we_w1[g*128 + 4*c4];
        float4 qv4 = *(const float4*)&qk2[pp][4*c4];
        s = fmaf(wv4.x, qv4.x, s);
        s = fmaf(wv4.y, qv4.y, s);
        s = fmaf(wv4.z, qv4.z, s);
        s = fmaf(wv4.w, qv4.w, s);
      }
      float val = (mat == 0) ? (tg - sg*s) : (sg*s);
      float* dst = (mat == 0) ? eqT : ekT;
      dst[(b*NPTS + n0 + pp)*8 + g] = val;
    } else {
      #pragma unroll
      for (int i = 0; i < 4; ++i){
        int f = t + 256*i;
        int pp = f >> 5, c4 = (f & 31)*4;
        float4 v = *(const float4*)&qk2[pp][c4];
        *(float4*)&vfT[((size_t)b*NPTS + n0 + pp)*CH + c4] = v;
      }
    }
    return;
  }

  // ================= k3 role (4 wave-units/block) =================
  int wv3 = t >> 6, lane = t & 63;
  u64 (*smBuf)[CAPQ] = (u64(*)[CAPQ])(smRaw + wv3*(QW*CAPQ*8));  // 4608 B/wave
  int unit = (grp*4 + (rem - 3))*4 + wv3;                 // 0..8191
  int b  = unit / (NPTS/QW);
  int q0 = (unit % (NPTS/QW)) * QW;
  const float4* P = pts + b*NPTS;

  #pragma unroll
  for (int s = 0; s < QW*CAPQ/64; ++s){
    int f = s*64 + lane;
    smBuf[f / CAPQ][f % CAPQ] = ~0ull;
  }

  float4 qp[QW];
  #pragma unroll
  for (int i = 0; i < QW; ++i) qp[i] = P[q0 + i];

  float T[QW];
  {
    float v0 = 3.402823466e38f, v1 = 3.402823466e38f;
    #pragma unroll
    for (int j = 0; j < 16; ++j){
      float4 c = P[lane + 64*j];
      v0 = fminf(v0, d2f(qp[0], c));
      v1 = fminf(v1, d2f(qp[1], c));
    }
    float t0 = v0, t1 = v1;
    #pragma unroll
    for (int r = 0; r < 16; ++r){
      float m0 = v0, m1 = v1;
      #pragma unroll
      for (int msk = 1; msk <= 32; msk <<= 1){
        m0 = fminf(m0, __shfl_xor(m0, msk));
        m1 = fminf(m1, __shfl_xor(m1, msk));
      }
      if (v0 == m0) v0 = 3.402823466e38f;
      if (v1 == m1) v1 = 3.402823466e38f;
      t0 = m0; t1 = m1;
    }
    T[0] = t0; T[1] = t1;
  }

  float Tlo[QW], Thi[QW]; int cnt[QW];
  #pragma unroll
  for (int i = 0; i < QW; ++i){ Tlo[i] = -3.0e38f; Thi[i] = 3.0e38f; cnt[i] = 0; }
  auto step = [&](float4 c, u32 m, int i){
    float d2 = d2f(qp[i], c);
    bool pred = d2 <= T[i];
    u64 bm = __ballot(pred);
    if (bm){
      int cc = __popcll(bm);
      if (pred && cnt[i] + cc <= CAPQ){
        int pos = cnt[i] + mbcnt64(bm);
        smBuf[i][pos] = (((u64)mono32(d2)) << 32) | m;
      }
      cnt[i] += cc;
    }
  };
  bool anybad = true;
  for (int att = 0; att < 16 && anybad; ++att){
    #pragma unroll
    for (int i = 0; i < QW; ++i) cnt[i] = 0;
    float4 c0 = P[lane], c1 = P[64 + lane], c2 = P[128 + lane], c3 = P[192 + lane];
    for (int base = 0; base < NPTS; base += 256){
      float4 e0 = c0, e1 = c1, e2 = c2, e3 = c3;
      int nb = base + 256;
      if (nb < NPTS){
        c0 = P[nb       + lane];
        c1 = P[nb +  64 + lane];
        c2 = P[nb + 128 + lane];
        c3 = P[nb + 192 + lane];
      }
      #pragma unroll
      for (int i = 0; i < QW; ++i){
        step(e0, (u32)(base       + lane), i);
        step(e1, (u32)(base +  64 + lane), i);
        step(e2, (u32)(base + 128 + lane), i);
        step(e3, (u32)(base + 192 + lane), i);
      }
    }
    anybad = false;
    #pragma unroll
    for (int i = 0; i < QW; ++i){
      if (cnt[i] > CAPQ){
        Thi[i] = T[i];
        T[i] = (Tlo[i] > -3.0e38f) ? 0.5f*(Tlo[i] + Thi[i])
                                   : ((T[i] > 0.f) ? T[i]*0.5f : T[i]*2.0f - 1.0f);
        anybad = true;
      } else if (cnt[i] < 16){
        Tlo[i] = T[i];
        T[i] = 0.5f*(Tlo[i] + Thi[i]);
        anybad = true;
      }
    }
  }

  {
    int cq0 = cnt[0] < CAPQ ? cnt[0] : CAPQ;
    int cq1 = cnt[1] < CAPQ ? cnt[1] : CAPQ;
    u64 a0, a1, a2, a3, a4, b0, b1, b2, b3, b4;
    a0 = (lane       < cq0) ? smBuf[0][lane      ] : ~0ull;
    a1 = (lane +  64 < cq0) ? smBuf[0][lane +  64] : ~0ull;
    a2 = (lane + 128 < cq0) ? smBuf[0][lane + 128] : ~0ull;
    a3 = (lane + 192 < cq0) ? smBuf[0][lane + 192] : ~0ull;
    a4 = (lane + 256 < cq0) ? smBuf[0][lane + 256] : ~0ull;
    b0 = (lane       < cq1) ? smBuf[1][lane      ] : ~0ull;
    b1 = (lane +  64 < cq1) ? smBuf[1][lane +  64] : ~0ull;
    b2 = (lane + 128 < cq1) ? smBuf[1][lane + 128] : ~0ull;
    b3 = (lane + 192 < cq1) ? smBuf[1][lane + 192] : ~0ull;
    b4 = (lane + 256 < cq1) ? smBuf[1][lane + 256] : ~0ull;
    #define CE_(x,y) { if (y < x){ u64 tm_ = x; x = y; y = tm_; } }
    CE_(a0,a1) CE_(a1,a2) CE_(a2,a3) CE_(a3,a4)
    CE_(a0,a1) CE_(a1,a2) CE_(a2,a3)
    CE_(a0,a1) CE_(a1,a2)
    CE_(a0,a1)
    CE_(b0,b1) CE_(b1,b2) CE_(b2,b3) CE_(b3,b4)
    CE_(b0,b1) CE_(b1,b2) CE_(b2,b3)
    CE_(b0,b1) CE_(b1,b2)
    CE_(b0,b1)
    #undef CE_
    int nq0 = q0, nq1 = q0 + 1;
    #pragma unroll
    for (int r = 0; r < 16; ++r){
      u64 g0 = a0, g1 = b0;
      #pragma unroll
      for (int msk = 1; msk <= 32; msk <<= 1){
        u64 o0 = shfl_xor_u64(g0, msk);
        u64 o1 = shfl_xor_u64(g1, msk);
        g0 = (o0 < g0) ? o0 : g0;
        g1 = (o1 < g1) ? o1 : g1;
      }
      if (a0 == g0){ a0 = a1; a1 = a2; a2 = a3; a3 = a4; a4 = ~0ull; }
      if (b0 == g1){ b0 = b1; b1 = b2; b2 = b3; b3 = b4; b4 = ~0ull; }
      if (lane == 0){
        idxout[(b*NPTS + nq0)*16 + r] = (g0 == ~0ull) ? nq0 : (int)(g0 & (u32)(NPTS-1));
        idxout[(b*NPTS + nq1)*16 + r] = (g1 == ~0ull) ? nq1 : (int)(g1 & (u32)(NPTS-1));
      }
    }
  }
}

// ---------------- K4: fused attention, 8 points/block ----------------
// Each wave handles 2 points sequentially in wave-local phases A+C (no extra
// barriers); phases D/E amortize the pe_w2 (64 KB) and wo (64 KB) streams over
// 8 points instead of 4 -> weight L2 traffic halves (536 -> 268 MB total).
#define H2S 136
#define K4P 8
__global__ __launch_bounds__(256, 3) void k4_attn(
    const float4* pts, const float* eqT, const float* ekT, const int* idxw,
    const float* vfT, const float* wsA, const float4* wsPW1, const float* wsWE2,
    const float* pe_w2, const float* wo,
    const float* bno_g, const float* bno_b, const float* bno_m, const float* bno_v,
    float* out){
  __shared__ __align__(16) float4 smW1[128];        // 2 KB
  __shared__ __align__(16) float4 smP[K4P][16];     // 2 KB  r-vectors
  __shared__ int   smJ[K4P][16];                    // 512 B neighbor indices
  __shared__ float smw[K4P][16][8];                 // 4 KB  weights [k][g]
  __shared__ __align__(16) float smH[K4P][8][H2S];  // 34.8 KB
  __shared__ __align__(16) float smOutv[K4P][128];  // 4 KB
  int t = threadIdx.x;
  int wv = t >> 6, lane = t & 63;
  int b  = blockIdx.x >> 10;          // NPTS/8 = 1024 blocks per batch
  int n0 = (blockIdx.x & 1023) * 8;
  if (t < 128) smW1[t] = wsPW1[t];
  __syncthreads();

  int k = lane >> 2, q = lane & 3;

  for (int r = 0; r < 2; ++r){
    int pl = wv + 4*r;
    int n = n0 + pl;
    int gq = b*NPTS + n;

    // ---- phase A (wave-local): logits + softmax weights ----
    {
      float4 pn  = pts[gq];
      float4 eqa = *(const float4*)&eqT[gq*8];
      float4 eqb = *(const float4*)&eqT[gq*8+4];
      int j = idxw[gq*16 + k] & (NPTS-1);
      int gj = b*NPTS + j;
      float4 pj  = pts[gj];
      float4 eka = *(const float4*)&ekT[gj*8];
      float4 ekb = *(const float4*)&ekT[gj*8+4];
      float rx = pj.x - pn.x, ry = pj.y - pn.y, rz = pj.z - pn.z;
      if (q == 0){
        smP[pl][k] = make_float4(rx, ry, rz, 0.f);
        smJ[pl][k] = j;
      }
      // ee added ONCE after the q-lane reduction
      float ee[8] = {eka.x+eqa.x, eka.y+eqa.y, eka.z+eqa.z, eka.w+eqa.w,
                     ekb.x+eqb.x, ekb.y+eqb.y, ekb.z+eqb.z, ekb.w+eqb.w};
      float lp[8] = {0.f,0.f,0.f,0.f,0.f,0.f,0.f,0.f};
      #pragma unroll
      for (int i = 0; i < 8; ++i){
        int hb = 4*q + 16*i;
        float4 w1;
        w1 = smW1[hb+0]; float hv0 = fmaxf(fmaf(w1.x, rx, fmaf(w1.y, ry, fmaf(w1.z, rz, w1.w))), 0.f);
        w1 = smW1[hb+1]; float hv1 = fmaxf(fmaf(w1.x, rx, fmaf(w1.y, ry, fmaf(w1.z, rz, w1.w))), 0.f);
        w1 = smW1[hb+2]; float hv2 = fmaxf(fmaf(w1.x, rx, fmaf(w1.y, ry, fmaf(w1.z, rz, w1.w))), 0.f);
        w1 = smW1[hb+3]; float hv3 = fmaxf(fmaf(w1.x, rx, fmaf(w1.y, ry, fmaf(w1.z, rz, w1.w))), 0.f);
        #pragma unroll
        for (int g = 0; g < 8; ++g){
          float4 a4 = *(const float4*)&wsA[g*128 + hb];
          lp[g] = fmaf(a4.x, hv0, lp[g]);
          lp[g] = fmaf(a4.y, hv1, lp[g]);
          lp[g] = fmaf(a4.z, hv2, lp[g]);
          lp[g] = fmaf(a4.w, hv3, lp[g]);
        }
      }
      #pragma unroll
      for (int g = 0; g < 8; ++g){
        lp[g] += __shfl_xor(lp[g], 1);
        lp[g] += __shfl_xor(lp[g], 2);
        lp[g] = fmaxf(lp[g] + ee[g], 0.f);
      }
      float lo0 = 0.f, lo1 = 0.f;
      #pragma unroll
      for (int g = 0; g < 8; ++g){
        lo0 = fmaf(wsWE2[(2*q+0)*8 + g], lp[g], lo0);
        lo1 = fmaf(wsWE2[(2*q+1)*8 + g], lp[g], lo1);
      }
      float m0 = lo0, m1 = lo1;
      #pragma unroll
      for (int msk = 4; msk <= 32; msk <<= 1){
        m0 = fmaxf(m0, __shfl_xor(m0, msk));
        m1 = fmaxf(m1, __shfl_xor(m1, msk));
      }
      float e0 = __expf(lo0 - m0), e1 = __expf(lo1 - m1);
      float s0 = e0, s1 = e1;
      #pragma unroll
      for (int msk = 4; msk <= 32; msk <<= 1){
        s0 += __shfl_xor(s0, msk);
        s1 += __shfl_xor(s1, msk);
      }
      smw[pl][k][2*q+0] = e0 / s0;
      smw[pl][k][2*q+1] = e1 / s1;
    }

    // ---- phase C (wave-local): H[g][h] = sum_k w[g,k]*relu(W1[h].r_k) ----
    {
      int g3 = lane >> 3, hh = lane & 7;
      float4 H4[4];
      #pragma unroll
      for (int ii = 0; ii < 4; ++ii) H4[ii] = make_float4(0.f,0.f,0.f,0.f);
      for (int kk = 0; kk < 16; ++kk){
        float4 r4 = smP[pl][kk];
        float wg  = smw[pl][kk][g3];
        #pragma unroll
        for (int ii = 0; ii < 4; ++ii){
          int hb = 4*hh + 32*ii;
          float4 w1;
          w1 = smW1[hb+0]; float hv0 = fmaxf(fmaf(w1.x, r4.x, fmaf(w1.y, r4.y, fmaf(w1.z, r4.z, w1.w))), 0.f);
          w1 = smW1[hb+1]; float hv1 = fmaxf(fmaf(w1.x, r4.x, fmaf(w1.y, r4.y, fmaf(w1.z, r4.z, w1.w))), 0.f);
          w1 = smW1[hb+2]; float hv2 = fmaxf(fmaf(w1.x, r4.x, fmaf(w1.y, r4.y, fmaf(w1.z, r4.z, w1.w))), 0.f);
          w1 = smW1[hb+3]; float hv3 = fmaxf(fmaf(w1.x, r4.x, fmaf(w1.y, r4.y, fmaf(w1.z, r4.z, w1.w))), 0.f);
          H4[ii].x = fmaf(wg, hv0, H4[ii].x);
          H4[ii].y = fmaf(wg, hv1, H4[ii].y);
          H4[ii].z = fmaf(wg, hv2, H4[ii].z);
          H4[ii].w = fmaf(wg, hv3, H4[ii].w);
        }
      }
      #pragma unroll
      for (int ii = 0; ii < 4; ++ii)
        *(float4*)&smH[pl][g3][4*hh + 32*ii] = H4[ii];
    }
  }
  __syncthreads();   // all waves' smH/smw/smJ visible block-wide

  // ---- phase D (block-wide, t<128): outv for all 8 points; pe_w2 rows read once ----
  if (t < 128){
    int c = t, g = c >> 4;
    float acc[K4P];
    #pragma unroll
    for (int pt = 0; pt < K4P; ++pt) acc[pt] = 0.f;
    for (int i = 0; i < 32; ++i){
      float4 pw = *(const float4*)&pe_w2[c*128 + 4*i];
      #pragma unroll
      for (int pt = 0; pt < K4P; ++pt){
        float4 h4 = *(const float4*)&smH[pt][g][4*i];
        acc[pt] = fmaf(pw.x, h4.x, acc[pt]);
        acc[pt] = fmaf(pw.y, h4.y, acc[pt]);
        acc[pt] = fmaf(pw.z, h4.z, acc[pt]);
        acc[pt] = fmaf(pw.w, h4.w, acc[pt]);
      }
    }
    #pragma unroll
    for (int pt = 0; pt < K4P; ++pt){
      #pragma unroll
      for (int kk = 0; kk < 16; ++kk){
        int jj = smJ[pt][kk];
        float wgk = smw[pt][kk][g];
        acc[pt] = fmaf(wgk, vfT[((size_t)b*NPTS + jj)*CH + c], acc[pt]);
      }
      smOutv[pt][c] = acc[pt];
    }
  }
  __syncthreads();

  // ---- phase E (t<128): out[o][n0..n0+7] = bno(wo @ outv), two float4 stores ----
  if (t < 128){
    int o = t;
    float so = bno_g[o] / sqrtf(bno_v[o] + EPSN);
    float bo = bno_b[o] - bno_m[o] * so;
    float fa[K4P];
    #pragma unroll
    for (int pt = 0; pt < K4P; ++pt) fa[pt] = 0.f;
    for (int i = 0; i < 32; ++i){
      float4 pw = *(const float4*)&wo[o*128 + 4*i];
      #pragma unroll
      for (int pt = 0; pt < K4P; ++pt){
        float4 h4 = *(const float4*)&smOutv[pt][4*i];
        fa[pt] = fmaf(pw.x, h4.x, fa[pt]);
        fa[pt] = fmaf(pw.y, h4.y, fa[pt]);
        fa[pt] = fmaf(pw.z, h4.z, fa[pt]);
        fa[pt] = fmaf(pw.w, h4.w, fa[pt]);
      }
    }
    float4 st0, st1;
    st0.x = fmaf(so, fa[0], bo);
    st0.y = fmaf(so, fa[1], bo);
    st0.z = fmaf(so, fa[2], bo);
    st0.w = fmaf(so, fa[3], bo);
    st1.x = fmaf(so, fa[4], bo);
    st1.y = fmaf(so, fa[5], bo);
    st1.z = fmaf(so, fa[6], bo);
    st1.w = fmaf(so, fa[7], bo);
    *(float4*)&out[((size_t)b*CH + o)*NPTS + n0]     = st0;
    *(float4*)&out[((size_t)b*CH + o)*NPTS + n0 + 4] = st1;
  }
}

extern "C" void kernel_launch(void* const* d_in, const int* in_sizes, int n_in,
                              void* d_out, int out_size, void* d_ws, size_t ws_size,
                              hipStream_t stream){
  const float* x     = (const float*)d_in[0];
  const float* xyz   = (const float*)d_in[1];
  const float* wq    = (const float*)d_in[2];
  const float* bnq_g = (const float*)d_in[3];
  const float* bnq_b = (const float*)d_in[4];
  const float* bnq_m = (const float*)d_in[5];
  const float* bnq_v = (const float*)d_in[6];
  const float* wk    = (const float*)d_in[7];
  const float* bnk_g = (const float*)d_in[8];
  const float* bnk_b = (const float*)d_in[9];
  const float* bnk_m = (const float*)d_in[10];
  const float* bnk_v = (const float*)d_in[11];
  const float* wv    = (const float*)d_in[12];
  const float* pe_w1 = (const float*)d_in[13];
  const float* pe_g  = (const float*)d_in[14];
  const float* pe_b  = (const float*)d_in[15];
  const float* pe_m  = (const float*)d_in[16];
  const float* pe_v  = (const float*)d_in[17];
  const float* pe_w2 = (const float*)d_in[18];
  const float* we_w1 = (const float*)d_in[19];
  const float* we_g  = (const float*)d_in[20];
  const float* we_b  = (const float*)d_in[21];
  const float* we_m  = (const float*)d_in[22];
  const float* we_v  = (const float*)d_in[23];
  const float* we_w2 = (const float*)d_in[24];
  const float* wo    = (const float*)d_in[25];
  const float* bno_g = (const float*)d_in[26];
  const float* bno_b = (const float*)d_in[27];
  const float* bno_m = (const float*)d_in[28];
  const float* bno_v = (const float*)d_in[29];

  char* ws = (char*)d_ws;
  float*  wsA   = (float*)(ws + WS_A);
  float4* wsPW1 = (float4*)(ws + WS_PW1);
  float*  wsWE2 = (float*)(ws + WS_WE2);
  float4* pts   = (float4*)(ws + WS_PTS);
  float*  eqT   = (float*)(ws + WS_EQ);
  float*  ekT   = (float*)(ws + WS_EK);
  int*    idxw  = (int*)(ws + WS_IDX);
  float*  vfT   = (float*)(ws + WS_VFT);
  float*  outp  = (float*)d_out;

  k0_precomp<<<dim3(1), dim3(256), 0, stream>>>(we_w1, pe_w2, pe_w1, we_g, we_v,
                                                pe_g, pe_b, pe_m, pe_v, we_w2,
                                                wsA, wsPW1, wsWE2);
  k1_pts<<<dim3(64), dim3(256), 0, stream>>>(xyz, pts);
  // 3584 blocks = 512 groups x (3 k2-role + 4 k3-role)
  k23_fused<<<dim3(3584), dim3(256), K23_LDS, stream>>>(x, wq, wk, wv,
                                               bnq_g, bnq_b, bnq_m, bnq_v,
                                               bnk_g, bnk_b, bnk_m, bnk_v,
                                               we_w1, we_g, we_b, we_m, we_v,
                                               eqT, ekT, vfT, pts, idxw);
  k4_attn<<<dim3(BATCH*(NPTS/K4P)), dim3(256), 0, stream>>>(pts, eqT, ekT, idxw, vfT,
                                                wsA, wsPW1, wsWE2, pe_w2, wo,
                                                bno_g, bno_b, bno_m, bno_v, outp);
}

// Round 19
// 493.335 us; speedup vs baseline: 1.0996x; 1.0918x over previous
//
#include <hip/hip_runtime.h>
#include <math.h>

typedef unsigned int u32;
typedef unsigned long long u64;

#define BATCH 2
#define CH 128
#define NPTS 8192
#define KNB 16
#define GRP 8
#define EPSN 1e-5f

// ---- workspace layout (bytes), total ~10.8 MB ----
#define WS_A     0           // 8*128 f32   A' = s_g * (we_w1 @ pe_w2)
#define WS_PW1   4096        // 128 float4  folded pe_w1 + pe_bn (sx,sy,sz,bias)
#define WS_WE2   6144        // 64 f32      we_w2
#define WS_PTS   8192        // 16384 float4 {x,y,z,|p|^2}
#define WS_EQ    270336      // B*N*8 f32   t_g - s_g*eq
#define WS_EK    794624      // B*N*8 f32   s_g*ek
#define WS_IDX   1318912     // B*N*16 int
#define WS_VFT   2367488     // B*N*128 f32 v transposed (point-major)

__device__ __forceinline__ float d2f(float4 a, float4 b){
  #pragma clang fp contract(off)
  float dot = a.x*b.x + a.y*b.y + a.z*b.z;
  return (a.w + b.w) - 2.0f*dot;
}
__device__ __forceinline__ u64 shfl_xor_u64(u64 v, int m){
  int lo = __shfl_xor((int)(u32)v, m);
  int hi = __shfl_xor((int)(u32)(v >> 32), m);
  return (((u64)(u32)hi) << 32) | (u32)lo;
}
__device__ __forceinline__ int mbcnt64(u64 bm){
  return (int)__builtin_amdgcn_mbcnt_hi((u32)(bm >> 32),
          __builtin_amdgcn_mbcnt_lo((u32)(bm & 0xFFFFFFFFull), 0u));
}
__device__ __forceinline__ u32 mono32(float d2){
  u32 db = __float_as_uint(d2);
  return (db & 0x80000000u) ? ~db : (db | 0x80000000u);  // monotone float->uint
}

// ---------------- K0: tiny precompute ----------------
__global__ __launch_bounds__(256) void k0_precomp(
    const float* we_w1, const float* pe_w2, const float* pe_w1,
    const float* we_g, const float* we_v,
    const float* pe_g, const float* pe_b, const float* pe_m, const float* pe_v,
    const float* we_w2, float* wsA, float4* wsPW1, float* wsWE2){
  int t = threadIdx.x;
  for (int i = t; i < 1024; i += 256){
    int g = i >> 7, h = i & 127;
    float s = 0.f;
    for (int c = 0; c < 128; ++c) s = fmaf(we_w1[g*128+c], pe_w2[c*128+h], s);
    float sg = we_g[g] / sqrtf(we_v[g] + EPSN);
    wsA[i] = s * sg;
  }
  if (t < 128){
    float s = pe_g[t] / sqrtf(pe_v[t] + EPSN);
    float bb = pe_b[t] - pe_m[t] * s;
    wsPW1[t] = make_float4(s*pe_w1[t*3+0], s*pe_w1[t*3+1], s*pe_w1[t*3+2], bb);
  }
  if (t < 64) wsWE2[t] = we_w2[t];
}

// ---------------- K1: points + squared norms ----------------
__global__ __launch_bounds__(256) void k1_pts(const float* xyz, float4* pts){
  int id = blockIdx.x*256 + threadIdx.x;
  if (id >= BATCH*NPTS) return;
  int b = id >> 13, n = id & (NPTS-1);
  float x = xyz[(b*3+0)*NPTS + n];
  float y = xyz[(b*3+1)*NPTS + n];
  float z = xyz[(b*3+2)*NPTS + n];
  float sq;
  {
    #pragma clang fp contract(off)
    sq = (x*x + y*y) + z*z;
  }
  pts[id] = make_float4(x, y, z, sq);
}

// ---------------- K23: fused projections (k2 role) + exact KNN (k3 role) ----------------
// Verbatim round-16 kernel (verified): roles interleaved 3:4 per 7-block group.
#define K2PTS 32
#define QW   2     // queries per k3 wave-unit
#define CAPQ 288   // candidate slots per query
#define K23_LDS 18432
__global__ __launch_bounds__(256) void k23_fused(
    const float* x, const float* wq, const float* wk, const float* wv,
    const float* bnq_g, const float* bnq_b, const float* bnq_m, const float* bnq_v,
    const float* bnk_g, const float* bnk_b, const float* bnk_m, const float* bnk_v,
    const float* we_w1,
    const float* we_g, const float* we_b, const float* we_m, const float* we_v,
    float* eqT, float* ekT, float* vfT,
    const float4* pts, int* idxout){
  extern __shared__ __align__(16) char smRaw[];
  int t = threadIdx.x;
  int grp = blockIdx.x / 7, rem = blockIdx.x % 7;

  if (rem < 3){
    // ================= k2 role =================
    float (*qk2)[129] = (float(*)[129])smRaw;            // 16512 B
    float* bnS = (float*)(smRaw + 16512);                // 512 B
    float* bnB = (float*)(smRaw + 17024);                // 512 B
    int bid2 = grp*3 + rem;                              // 0..1535
    int mat = bid2 % 3;
    int tmp = bid2 / 3;
    int b   = tmp / (NPTS/K2PTS);
    int n0  = (tmp % (NPTS/K2PTS)) * K2PTS;
    int p = t & 31, og = t >> 5;
    const float* xp = x + (size_t)b*CH*NPTS + n0 + p;
    const float* W = (mat == 0) ? wq : ((mat == 1) ? wk : wv);
    if (mat < 2 && t < 128){
      const float* g_ = mat==0 ? bnq_g : bnk_g;
      const float* b_ = mat==0 ? bnq_b : bnk_b;
      const float* m_ = mat==0 ? bnq_m : bnk_m;
      const float* v_ = mat==0 ? bnq_v : bnk_v;
      float s = g_[t] / sqrtf(v_[t] + EPSN);
      bnS[t] = s;
      bnB[t] = b_[t] - m_[t] * s;
    }
    __syncthreads();
    float acc[16];
    #pragma unroll
    for (int ii = 0; ii < 16; ++ii) acc[ii] = 0.f;
    for (int dd = 0; dd < 32; ++dd){
      float x0 = xp[(size_t)(4*dd+0)*NPTS];
      float x1 = xp[(size_t)(4*dd+1)*NPTS];
      float x2 = xp[(size_t)(4*dd+2)*NPTS];
      float x3 = xp[(size_t)(4*dd+3)*NPTS];
      #pragma unroll
      for (int ii = 0; ii < 16; ++ii){
        int o = og*16 + ii;
        float4 wu = *(const float4*)&W[o*128 + 4*dd];
        acc[ii] = fmaf(wu.x, x0, acc[ii]);
        acc[ii] = fmaf(wu.y, x1, acc[ii]);
        acc[ii] = fmaf(wu.z, x2, acc[ii]);
        acc[ii] = fmaf(wu.w, x3, acc[ii]);
      }
    }
    #pragma unroll
    for (int ii = 0; ii < 16; ++ii){
      int o = og*16 + ii;
      float v = acc[ii];
      if (mat < 2) v = fmaxf(fmaf(bnS[o], v, bnB[o]), 0.f);
      qk2[p][o] = v;
    }
    __syncthreads();
    if (mat < 2){
      int g = t >> 5, pp = t & 31;
      float sg = we_g[g] / sqrtf(we_v[g] + EPSN);
      float tg = we_b[g] - we_m[g] * sg;
      float s = 0.f;
      for (int c4 = 0; c4 < 32; ++c4){
        float4 wv4 = *(const float4*)&we_w1[g*128 + 4*c4];
        float4 qv4 = *(const float4*)&qk2[pp][4*c4];
        s = fmaf(wv4.x, qv4.x, s);
        s = fmaf(wv4.y, qv4.y, s);
        s = fmaf(wv4.z, qv4.z, s);
        s = fmaf(wv4.w, qv4.w, s);
      }
      float val = (mat == 0) ? (tg - sg*s) : (sg*s);
      float* dst = (mat == 0) ? eqT : ekT;
      dst[(b*NPTS + n0 + pp)*8 + g] = val;
    } else {
      #pragma unroll
      for (int i = 0; i < 4; ++i){
        int f = t + 256*i;
        int pp = f >> 5, c4 = (f & 31)*4;
        float4 v = *(const float4*)&qk2[pp][c4];
        *(float4*)&vfT[((size_t)b*NPTS + n0 + pp)*CH + c4] = v;
      }
    }
    return;
  }

  // ================= k3 role (4 wave-units/block) =================
  int wv3 = t >> 6, lane = t & 63;
  u64 (*smBuf)[CAPQ] = (u64(*)[CAPQ])(smRaw + wv3*(QW*CAPQ*8));  // 4608 B/wave
  int unit = (grp*4 + (rem - 3))*4 + wv3;                 // 0..8191
  int b  = unit / (NPTS/QW);
  int q0 = (unit % (NPTS/QW)) * QW;
  const float4* P = pts + b*NPTS;

  #pragma unroll
  for (int s = 0; s < QW*CAPQ/64; ++s){
    int f = s*64 + lane;
    smBuf[f / CAPQ][f % CAPQ] = ~0ull;
  }

  float4 qp[QW];
  #pragma unroll
  for (int i = 0; i < QW; ++i) qp[i] = P[q0 + i];

  float T[QW];
  {
    float v0 = 3.402823466e38f, v1 = 3.402823466e38f;
    #pragma unroll
    for (int j = 0; j < 16; ++j){
      float4 c = P[lane + 64*j];
      v0 = fminf(v0, d2f(qp[0], c));
      v1 = fminf(v1, d2f(qp[1], c));
    }
    float t0 = v0, t1 = v1;
    #pragma unroll
    for (int r = 0; r < 16; ++r){
      float m0 = v0, m1 = v1;
      #pragma unroll
      for (int msk = 1; msk <= 32; msk <<= 1){
        m0 = fminf(m0, __shfl_xor(m0, msk));
        m1 = fminf(m1, __shfl_xor(m1, msk));
      }
      if (v0 == m0) v0 = 3.402823466e38f;
      if (v1 == m1) v1 = 3.402823466e38f;
      t0 = m0; t1 = m1;
    }
    T[0] = t0; T[1] = t1;
  }

  float Tlo[QW], Thi[QW]; int cnt[QW];
  #pragma unroll
  for (int i = 0; i < QW; ++i){ Tlo[i] = -3.0e38f; Thi[i] = 3.0e38f; cnt[i] = 0; }
  auto step = [&](float4 c, u32 m, int i){
    float d2 = d2f(qp[i], c);
    bool pred = d2 <= T[i];
    u64 bm = __ballot(pred);
    if (bm){
      int cc = __popcll(bm);
      if (pred && cnt[i] + cc <= CAPQ){
        int pos = cnt[i] + mbcnt64(bm);
        smBuf[i][pos] = (((u64)mono32(d2)) << 32) | m;
      }
      cnt[i] += cc;
    }
  };
  bool anybad = true;
  for (int att = 0; att < 16 && anybad; ++att){
    #pragma unroll
    for (int i = 0; i < QW; ++i) cnt[i] = 0;
    float4 c0 = P[lane], c1 = P[64 + lane], c2 = P[128 + lane], c3 = P[192 + lane];
    for (int base = 0; base < NPTS; base += 256){
      float4 e0 = c0, e1 = c1, e2 = c2, e3 = c3;
      int nb = base + 256;
      if (nb < NPTS){
        c0 = P[nb       + lane];
        c1 = P[nb +  64 + lane];
        c2 = P[nb + 128 + lane];
        c3 = P[nb + 192 + lane];
      }
      #pragma unroll
      for (int i = 0; i < QW; ++i){
        step(e0, (u32)(base       + lane), i);
        step(e1, (u32)(base +  64 + lane), i);
        step(e2, (u32)(base + 128 + lane), i);
        step(e3, (u32)(base + 192 + lane), i);
      }
    }
    anybad = false;
    #pragma unroll
    for (int i = 0; i < QW; ++i){
      if (cnt[i] > CAPQ){
        Thi[i] = T[i];
        T[i] = (Tlo[i] > -3.0e38f) ? 0.5f*(Tlo[i] + Thi[i])
                                   : ((T[i] > 0.f) ? T[i]*0.5f : T[i]*2.0f - 1.0f);
        anybad = true;
      } else if (cnt[i] < 16){
        Tlo[i] = T[i];
        T[i] = 0.5f*(Tlo[i] + Thi[i]);
        anybad = true;
      }
    }
  }

  {
    int cq0 = cnt[0] < CAPQ ? cnt[0] : CAPQ;
    int cq1 = cnt[1] < CAPQ ? cnt[1] : CAPQ;
    u64 a0, a1, a2, a3, a4, b0, b1, b2, b3, b4;
    a0 = (lane       < cq0) ? smBuf[0][lane      ] : ~0ull;
    a1 = (lane +  64 < cq0) ? smBuf[0][lane +  64] : ~0ull;
    a2 = (lane + 128 < cq0) ? smBuf[0][lane + 128] : ~0ull;
    a3 = (lane + 192 < cq0) ? smBuf[0][lane + 192] : ~0ull;
    a4 = (lane + 256 < cq0) ? smBuf[0][lane + 256] : ~0ull;
    b0 = (lane       < cq1) ? smBuf[1][lane      ] : ~0ull;
    b1 = (lane +  64 < cq1) ? smBuf[1][lane +  64] : ~0ull;
    b2 = (lane + 128 < cq1) ? smBuf[1][lane + 128] : ~0ull;
    b3 = (lane + 192 < cq1) ? smBuf[1][lane + 192] : ~0ull;
    b4 = (lane + 256 < cq1) ? smBuf[1][lane + 256] : ~0ull;
    #define CE_(x,y) { if (y < x){ u64 tm_ = x; x = y; y = tm_; } }
    CE_(a0,a1) CE_(a1,a2) CE_(a2,a3) CE_(a3,a4)
    CE_(a0,a1) CE_(a1,a2) CE_(a2,a3)
    CE_(a0,a1) CE_(a1,a2)
    CE_(a0,a1)
    CE_(b0,b1) CE_(b1,b2) CE_(b2,b3) CE_(b3,b4)
    CE_(b0,b1) CE_(b1,b2) CE_(b2,b3)
    CE_(b0,b1) CE_(b1,b2)
    CE_(b0,b1)
    #undef CE_
    int nq0 = q0, nq1 = q0 + 1;
    #pragma unroll
    for (int r = 0; r < 16; ++r){
      u64 g0 = a0, g1 = b0;
      #pragma unroll
      for (int msk = 1; msk <= 32; msk <<= 1){
        u64 o0 = shfl_xor_u64(g0, msk);
        u64 o1 = shfl_xor_u64(g1, msk);
        g0 = (o0 < g0) ? o0 : g0;
        g1 = (o1 < g1) ? o1 : g1;
      }
      if (a0 == g0){ a0 = a1; a1 = a2; a2 = a3; a3 = a4; a4 = ~0ull; }
      if (b0 == g1){ b0 = b1; b1 = b2; b2 = b3; b3 = b4; b4 = ~0ull; }
      if (lane == 0){
        idxout[(b*NPTS + nq0)*16 + r] = (g0 == ~0ull) ? nq0 : (int)(g0 & (u32)(NPTS-1));
        idxout[(b*NPTS + nq1)*16 + r] = (g1 == ~0ull) ? nq1 : (int)(g1 & (u32)(NPTS-1));
      }
    }
  }
}

// ---------------- K4: fused attention, 8 points/block, spill-free ----------------
// Round-18 post-mortem: __launch_bounds__(256,3) + pipelined 2-iter r-loop made
// the compiler spill ~1 KB/thread to scratch (510 MB HBM writes). Fix: min-waves
// 2 (VGPR cap 256; LDS already limits to 3 blocks/CU so no occupancy loss) and
// #pragma unroll 1 on the r-loop (each iteration is wave-local; no cross-iter
// pipelining needed). Weight streams (pe_w2, wo) still amortized over 8 points.
#define H2S 136
#define K4P 8
__global__ __launch_bounds__(256, 2) void k4_attn(
    const float4* pts, const float* eqT, const float* ekT, const int* idxw,
    const float* vfT, const float* wsA, const float4* wsPW1, const float* wsWE2,
    const float* pe_w2, const float* wo,
    const float* bno_g, const float* bno_b, const float* bno_m, const float* bno_v,
    float* out){
  __shared__ __align__(16) float4 smW1[128];        // 2 KB
  __shared__ __align__(16) float4 smP[K4P][16];     // 2 KB  r-vectors
  __shared__ int   smJ[K4P][16];                    // 512 B neighbor indices
  __shared__ float smw[K4P][16][8];                 // 4 KB  weights [k][g]
  __shared__ __align__(16) float smH[K4P][8][H2S];  // 34.8 KB
  __shared__ __align__(16) float smOutv[K4P][128];  // 4 KB
  int t = threadIdx.x;
  int wv = t >> 6, lane = t & 63;
  int b  = blockIdx.x >> 10;          // NPTS/8 = 1024 blocks per batch
  int n0 = (blockIdx.x & 1023) * 8;
  if (t < 128) smW1[t] = wsPW1[t];
  __syncthreads();

  int k = lane >> 2, q = lane & 3;

  #pragma unroll 1
  for (int r = 0; r < 2; ++r){
    int pl = wv + 4*r;
    int n = n0 + pl;
    int gq = b*NPTS + n;

    // ---- phase A (wave-local): logits + softmax weights ----
    {
      float4 pn  = pts[gq];
      float4 eqa = *(const float4*)&eqT[gq*8];
      float4 eqb = *(const float4*)&eqT[gq*8+4];
      int j = idxw[gq*16 + k] & (NPTS-1);
      int gj = b*NPTS + j;
      float4 pj  = pts[gj];
      float4 eka = *(const float4*)&ekT[gj*8];
      float4 ekb = *(const float4*)&ekT[gj*8+4];
      float rx = pj.x - pn.x, ry = pj.y - pn.y, rz = pj.z - pn.z;
      if (q == 0){
        smP[pl][k] = make_float4(rx, ry, rz, 0.f);
        smJ[pl][k] = j;
      }
      // ee added ONCE after the q-lane reduction
      float ee[8] = {eka.x+eqa.x, eka.y+eqa.y, eka.z+eqa.z, eka.w+eqa.w,
                     ekb.x+eqb.x, ekb.y+eqb.y, ekb.z+eqb.z, ekb.w+eqb.w};
      float lp[8] = {0.f,0.f,0.f,0.f,0.f,0.f,0.f,0.f};
      #pragma unroll
      for (int i = 0; i < 8; ++i){
        int hb = 4*q + 16*i;
        float4 w1;
        w1 = smW1[hb+0]; float hv0 = fmaxf(fmaf(w1.x, rx, fmaf(w1.y, ry, fmaf(w1.z, rz, w1.w))), 0.f);
        w1 = smW1[hb+1]; float hv1 = fmaxf(fmaf(w1.x, rx, fmaf(w1.y, ry, fmaf(w1.z, rz, w1.w))), 0.f);
        w1 = smW1[hb+2]; float hv2 = fmaxf(fmaf(w1.x, rx, fmaf(w1.y, ry, fmaf(w1.z, rz, w1.w))), 0.f);
        w1 = smW1[hb+3]; float hv3 = fmaxf(fmaf(w1.x, rx, fmaf(w1.y, ry, fmaf(w1.z, rz, w1.w))), 0.f);
        #pragma unroll
        for (int g = 0; g < 8; ++g){
          float4 a4 = *(const float4*)&wsA[g*128 + hb];
          lp[g] = fmaf(a4.x, hv0, lp[g]);
          lp[g] = fmaf(a4.y, hv1, lp[g]);
          lp[g] = fmaf(a4.z, hv2, lp[g]);
          lp[g] = fmaf(a4.w, hv3, lp[g]);
        }
      }
      #pragma unroll
      for (int g = 0; g < 8; ++g){
        lp[g] += __shfl_xor(lp[g], 1);
        lp[g] += __shfl_xor(lp[g], 2);
        lp[g] = fmaxf(lp[g] + ee[g], 0.f);
      }
      float lo0 = 0.f, lo1 = 0.f;
      #pragma unroll
      for (int g = 0; g < 8; ++g){
        lo0 = fmaf(wsWE2[(2*q+0)*8 + g], lp[g], lo0);
        lo1 = fmaf(wsWE2[(2*q+1)*8 + g], lp[g], lo1);
      }
      float m0 = lo0, m1 = lo1;
      #pragma unroll
      for (int msk = 4; msk <= 32; msk <<= 1){
        m0 = fmaxf(m0, __shfl_xor(m0, msk));
        m1 = fmaxf(m1, __shfl_xor(m1, msk));
      }
      float e0 = __expf(lo0 - m0), e1 = __expf(lo1 - m1);
      float s0 = e0, s1 = e1;
      #pragma unroll
      for (int msk = 4; msk <= 32; msk <<= 1){
        s0 += __shfl_xor(s0, msk);
        s1 += __shfl_xor(s1, msk);
      }
      smw[pl][k][2*q+0] = e0 / s0;
      smw[pl][k][2*q+1] = e1 / s1;
    }

    // ---- phase C (wave-local): H[g][h] = sum_k w[g,k]*relu(W1[h].r_k) ----
    {
      int g3 = lane >> 3, hh = lane & 7;
      float4 H4[4];
      #pragma unroll
      for (int ii = 0; ii < 4; ++ii) H4[ii] = make_float4(0.f,0.f,0.f,0.f);
      for (int kk = 0; kk < 16; ++kk){
        float4 r4 = smP[pl][kk];
        float wg  = smw[pl][kk][g3];
        #pragma unroll
        for (int ii = 0; ii < 4; ++ii){
          int hb = 4*hh + 32*ii;
          float4 w1;
          w1 = smW1[hb+0]; float hv0 = fmaxf(fmaf(w1.x, r4.x, fmaf(w1.y, r4.y, fmaf(w1.z, r4.z, w1.w))), 0.f);
          w1 = smW1[hb+1]; float hv1 = fmaxf(fmaf(w1.x, r4.x, fmaf(w1.y, r4.y, fmaf(w1.z, r4.z, w1.w))), 0.f);
          w1 = smW1[hb+2]; float hv2 = fmaxf(fmaf(w1.x, r4.x, fmaf(w1.y, r4.y, fmaf(w1.z, r4.z, w1.w))), 0.f);
          w1 = smW1[hb+3]; float hv3 = fmaxf(fmaf(w1.x, r4.x, fmaf(w1.y, r4.y, fmaf(w1.z, r4.z, w1.w))), 0.f);
          H4[ii].x = fmaf(wg, hv0, H4[ii].x);
          H4[ii].y = fmaf(wg, hv1, H4[ii].y);
          H4[ii].z = fmaf(wg, hv2, H4[ii].z);
          H4[ii].w = fmaf(wg, hv3, H4[ii].w);
        }
      }
      #pragma unroll
      for (int ii = 0; ii < 4; ++ii)
        *(float4*)&smH[pl][g3][4*hh + 32*ii] = H4[ii];
    }
  }
  __syncthreads();   // all waves' smH/smw/smJ visible block-wide

  // ---- phase D (block-wide, t<128): outv for all 8 points; pe_w2 rows read once ----
  if (t < 128){
    int c = t, g = c >> 4;
    float acc[K4P];
    #pragma unroll
    for (int pt = 0; pt < K4P; ++pt) acc[pt] = 0.f;
    for (int i = 0; i < 32; ++i){
      float4 pw = *(const float4*)&pe_w2[c*128 + 4*i];
      #pragma unroll
      for (int pt = 0; pt < K4P; ++pt){
        float4 h4 = *(const float4*)&smH[pt][g][4*i];
        acc[pt] = fmaf(pw.x, h4.x, acc[pt]);
        acc[pt] = fmaf(pw.y, h4.y, acc[pt]);
        acc[pt] = fmaf(pw.z, h4.z, acc[pt]);
        acc[pt] = fmaf(pw.w, h4.w, acc[pt]);
      }
    }
    #pragma unroll
    for (int pt = 0; pt < K4P; ++pt){
      #pragma unroll
      for (int kk = 0; kk < 16; ++kk){
        int jj = smJ[pt][kk];
        float wgk = smw[pt][kk][g];
        acc[pt] = fmaf(wgk, vfT[((size_t)b*NPTS + jj)*CH + c], acc[pt]);
      }
      smOutv[pt][c] = acc[pt];
    }
  }
  __syncthreads();

  // ---- phase E (t<128): out[o][n0..n0+7] = bno(wo @ outv), two float4 stores ----
  if (t < 128){
    int o = t;
    float so = bno_g[o] / sqrtf(bno_v[o] + EPSN);
    float bo = bno_b[o] - bno_m[o] * so;
    float fa[K4P];
    #pragma unroll
    for (int pt = 0; pt < K4P; ++pt) fa[pt] = 0.f;
    for (int i = 0; i < 32; ++i){
      float4 pw = *(const float4*)&wo[o*128 + 4*i];
      #pragma unroll
      for (int pt = 0; pt < K4P; ++pt){
        float4 h4 = *(const float4*)&smOutv[pt][4*i];
        fa[pt] = fmaf(pw.x, h4.x, fa[pt]);
        fa[pt] = fmaf(pw.y, h4.y, fa[pt]);
        fa[pt] = fmaf(pw.z, h4.z, fa[pt]);
        fa[pt] = fmaf(pw.w, h4.w, fa[pt]);
      }
    }
    float4 st0, st1;
    st0.x = fmaf(so, fa[0], bo);
    st0.y = fmaf(so, fa[1], bo);
    st0.z = fmaf(so, fa[2], bo);
    st0.w = fmaf(so, fa[3], bo);
    st1.x = fmaf(so, fa[4], bo);
    st1.y = fmaf(so, fa[5], bo);
    st1.z = fmaf(so, fa[6], bo);
    st1.w = fmaf(so, fa[7], bo);
    *(float4*)&out[((size_t)b*CH + o)*NPTS + n0]     = st0;
    *(float4*)&out[((size_t)b*CH + o)*NPTS + n0 + 4] = st1;
  }
}

extern "C" void kernel_launch(void* const* d_in, const int* in_sizes, int n_in,
                              void* d_out, int out_size, void* d_ws, size_t ws_size,
                              hipStream_t stream){
  const float* x     = (const float*)d_in[0];
  const float* xyz   = (const float*)d_in[1];
  const float* wq    = (const float*)d_in[2];
  const float* bnq_g = (const float*)d_in[3];
  const float* bnq_b = (const float*)d_in[4];
  const float* bnq_m = (const float*)d_in[5];
  const float* bnq_v = (const float*)d_in[6];
  const float* wk    = (const float*)d_in[7];
  const float* bnk_g = (const float*)d_in[8];
  const float* bnk_b = (const float*)d_in[9];
  const float* bnk_m = (const float*)d_in[10];
  const float* bnk_v = (const float*)d_in[11];
  const float* wv    = (const float*)d_in[12];
  const float* pe_w1 = (const float*)d_in[13];
  const float* pe_g  = (const float*)d_in[14];
  const float* pe_b  = (const float*)d_in[15];
  const float* pe_m  = (const float*)d_in[16];
  const float* pe_v  = (const float*)d_in[17];
  const float* pe_w2 = (const float*)d_in[18];
  const float* we_w1 = (const float*)d_in[19];
  const float* we_g  = (const float*)d_in[20];
  const float* we_b  = (const float*)d_in[21];
  const float* we_m  = (const float*)d_in[22];
  const float* we_v  = (const float*)d_in[23];
  const float* we_w2 = (const float*)d_in[24];
  const float* wo    = (const float*)d_in[25];
  const float* bno_g = (const float*)d_in[26];
  const float* bno_b = (const float*)d_in[27];
  const float* bno_m = (const float*)d_in[28];
  const float* bno_v = (const float*)d_in[29];

  char* ws = (char*)d_ws;
  float*  wsA   = (float*)(ws + WS_A);
  float4* wsPW1 = (float4*)(ws + WS_PW1);
  float*  wsWE2 = (float*)(ws + WS_WE2);
  float4* pts   = (float4*)(ws + WS_PTS);
  float*  eqT   = (float*)(ws + WS_EQ);
  float*  ekT   = (float*)(ws + WS_EK);
  int*    idxw  = (int*)(ws + WS_IDX);
  float*  vfT   = (float*)(ws + WS_VFT);
  float*  outp  = (float*)d_out;

  k0_precomp<<<dim3(1), dim3(256), 0, stream>>>(we_w1, pe_w2, pe_w1, we_g, we_v,
                                                pe_g, pe_b, pe_m, pe_v, we_w2,
                                                wsA, wsPW1, wsWE2);
  k1_pts<<<dim3(64), dim3(256), 0, stream>>>(xyz, pts);
  // 3584 blocks = 512 groups x (3 k2-role + 4 k3-role)
  k23_fused<<<dim3(3584), dim3(256), K23_LDS, stream>>>(x, wq, wk, wv,
                                               bnq_g, bnq_b, bnq_m, bnq_v,
                                               bnk_g, bnk_b, bnk_m, bnk_v,
                                               we_w1, we_g, we_b, we_m, we_v,
                                               eqT, ekT, vfT, pts, idxw);
  k4_attn<<<dim3(BATCH*(NPTS/K4P)), dim3(256), 0, stream>>>(pts, eqT, ekT, idxw, vfT,
                                                wsA, wsPW1, wsWE2, pe_w2, wo,
                                                bno_g, bno_b, bno_m, bno_v, outp);
}

// Round 20
// 327.848 us; speedup vs baseline: 1.6547x; 1.5048x over previous
//
#include <hip/hip_runtime.h>
#include <math.h>

typedef unsigned int u32;
typedef unsigned long long u64;

#define BATCH 2
#define CH 128
#define NPTS 8192
#define KNB 16
#define GRP 8
#define EPSN 1e-5f

// ---- workspace layout (bytes), total ~10.8 MB ----
#define WS_A     0           // 8*128 f32   A' = s_g * (we_w1 @ pe_w2)
#define WS_PW1   4096        // 128 float4  folded pe_w1 + pe_bn (sx,sy,sz,bias)
#define WS_WE2   6144        // 64 f32      we_w2
#define WS_PTS   8192        // 16384 float4 {x,y,z,|p|^2}
#define WS_EQ    270336      // B*N*8 f32   t_g - s_g*eq
#define WS_EK    794624      // B*N*8 f32   s_g*ek
#define WS_IDX   1318912     // B*N*16 int
#define WS_VFT   2367488     // B*N*128 f32 v transposed (point-major)

__device__ __forceinline__ float d2f(float4 a, float4 b){
  #pragma clang fp contract(off)
  float dot = a.x*b.x + a.y*b.y + a.z*b.z;
  return (a.w + b.w) - 2.0f*dot;
}
__device__ __forceinline__ u64 shfl_xor_u64(u64 v, int m){
  int lo = __shfl_xor((int)(u32)v, m);
  int hi = __shfl_xor((int)(u32)(v >> 32), m);
  return (((u64)(u32)hi) << 32) | (u32)lo;
}
__device__ __forceinline__ int mbcnt64(u64 bm){
  return (int)__builtin_amdgcn_mbcnt_hi((u32)(bm >> 32),
          __builtin_amdgcn_mbcnt_lo((u32)(bm & 0xFFFFFFFFull), 0u));
}
__device__ __forceinline__ u32 mono32(float d2){
  u32 db = __float_as_uint(d2);
  return (db & 0x80000000u) ? ~db : (db | 0x80000000u);  // monotone float->uint
}

// ---------------- K0: tiny precompute ----------------
__global__ __launch_bounds__(256) void k0_precomp(
    const float* we_w1, const float* pe_w2, const float* pe_w1,
    const float* we_g, const float* we_v,
    const float* pe_g, const float* pe_b, const float* pe_m, const float* pe_v,
    const float* we_w2, float* wsA, float4* wsPW1, float* wsWE2){
  int t = threadIdx.x;
  for (int i = t; i < 1024; i += 256){
    int g = i >> 7, h = i & 127;
    float s = 0.f;
    for (int c = 0; c < 128; ++c) s = fmaf(we_w1[g*128+c], pe_w2[c*128+h], s);
    float sg = we_g[g] / sqrtf(we_v[g] + EPSN);
    wsA[i] = s * sg;
  }
  if (t < 128){
    float s = pe_g[t] / sqrtf(pe_v[t] + EPSN);
    float bb = pe_b[t] - pe_m[t] * s;
    wsPW1[t] = make_float4(s*pe_w1[t*3+0], s*pe_w1[t*3+1], s*pe_w1[t*3+2], bb);
  }
  if (t < 64) wsWE2[t] = we_w2[t];
}

// ---------------- K1: points + squared norms ----------------
__global__ __launch_bounds__(256) void k1_pts(const float* xyz, float4* pts){
  int id = blockIdx.x*256 + threadIdx.x;
  if (id >= BATCH*NPTS) return;
  int b = id >> 13, n = id & (NPTS-1);
  float x = xyz[(b*3+0)*NPTS + n];
  float y = xyz[(b*3+1)*NPTS + n];
  float z = xyz[(b*3+2)*NPTS + n];
  float sq;
  {
    #pragma clang fp contract(off)
    sq = (x*x + y*y) + z*z;
  }
  pts[id] = make_float4(x, y, z, sq);
}

// ---------------- K23: fused projections (k2 role) + exact KNN (k3 role) ----------------
// Verbatim round-16 kernel (verified): roles interleaved 3:4 per 7-block group.
#define K2PTS 32
#define QW   2     // queries per k3 wave-unit
#define CAPQ 288   // candidate slots per query
#define K23_LDS 18432
__global__ __launch_bounds__(256) void k23_fused(
    const float* x, const float* wq, const float* wk, const float* wv,
    const float* bnq_g, const float* bnq_b, const float* bnq_m, const float* bnq_v,
    const float* bnk_g, const float* bnk_b, const float* bnk_m, const float* bnk_v,
    const float* we_w1,
    const float* we_g, const float* we_b, const float* we_m, const float* we_v,
    float* eqT, float* ekT, float* vfT,
    const float4* pts, int* idxout){
  extern __shared__ __align__(16) char smRaw[];
  int t = threadIdx.x;
  int grp = blockIdx.x / 7, rem = blockIdx.x % 7;

  if (rem < 3){
    // ================= k2 role =================
    float (*qk2)[129] = (float(*)[129])smRaw;            // 16512 B
    float* bnS = (float*)(smRaw + 16512);                // 512 B
    float* bnB = (float*)(smRaw + 17024);                // 512 B
    int bid2 = grp*3 + rem;                              // 0..1535
    int mat = bid2 % 3;
    int tmp = bid2 / 3;
    int b   = tmp / (NPTS/K2PTS);
    int n0  = (tmp % (NPTS/K2PTS)) * K2PTS;
    int p = t & 31, og = t >> 5;
    const float* xp = x + (size_t)b*CH*NPTS + n0 + p;
    const float* W = (mat == 0) ? wq : ((mat == 1) ? wk : wv);
    if (mat < 2 && t < 128){
      const float* g_ = mat==0 ? bnq_g : bnk_g;
      const float* b_ = mat==0 ? bnq_b : bnk_b;
      const float* m_ = mat==0 ? bnq_m : bnk_m;
      const float* v_ = mat==0 ? bnq_v : bnk_v;
      float s = g_[t] / sqrtf(v_[t] + EPSN);
      bnS[t] = s;
      bnB[t] = b_[t] - m_[t] * s;
    }
    __syncthreads();
    float acc[16];
    #pragma unroll
    for (int ii = 0; ii < 16; ++ii) acc[ii] = 0.f;
    for (int dd = 0; dd < 32; ++dd){
      float x0 = xp[(size_t)(4*dd+0)*NPTS];
      float x1 = xp[(size_t)(4*dd+1)*NPTS];
      float x2 = xp[(size_t)(4*dd+2)*NPTS];
      float x3 = xp[(size_t)(4*dd+3)*NPTS];
      #pragma unroll
      for (int ii = 0; ii < 16; ++ii){
        int o = og*16 + ii;
        float4 wu = *(const float4*)&W[o*128 + 4*dd];
        acc[ii] = fmaf(wu.x, x0, acc[ii]);
        acc[ii] = fmaf(wu.y, x1, acc[ii]);
        acc[ii] = fmaf(wu.z, x2, acc[ii]);
        acc[ii] = fmaf(wu.w, x3, acc[ii]);
      }
    }
    #pragma unroll
    for (int ii = 0; ii < 16; ++ii){
      int o = og*16 + ii;
      float v = acc[ii];
      if (mat < 2) v = fmaxf(fmaf(bnS[o], v, bnB[o]), 0.f);
      qk2[p][o] = v;
    }
    __syncthreads();
    if (mat < 2){
      int g = t >> 5, pp = t & 31;
      float sg = we_g[g] / sqrtf(we_v[g] + EPSN);
      float tg = we_b[g] - we_m[g] * sg;
      float s = 0.f;
      for (int c4 = 0; c4 < 32; ++c4){
        float4 wv4 = *(const float4*)&we_w1[g*128 + 4*c4];
        float4 qv4 = *(const float4*)&qk2[pp][4*c4];
        s = fmaf(wv4.x, qv4.x, s);
        s = fmaf(wv4.y, qv4.y, s);
        s = fmaf(wv4.z, qv4.z, s);
        s = fmaf(wv4.w, qv4.w, s);
      }
      float val = (mat == 0) ? (tg - sg*s) : (sg*s);
      float* dst = (mat == 0) ? eqT : ekT;
      dst[(b*NPTS + n0 + pp)*8 + g] = val;
    } else {
      #pragma unroll
      for (int i = 0; i < 4; ++i){
        int f = t + 256*i;
        int pp = f >> 5, c4 = (f & 31)*4;
        float4 v = *(const float4*)&qk2[pp][c4];
        *(float4*)&vfT[((size_t)b*NPTS + n0 + pp)*CH + c4] = v;
      }
    }
    return;
  }

  // ================= k3 role (4 wave-units/block) =================
  int wv3 = t >> 6, lane = t & 63;
  u64 (*smBuf)[CAPQ] = (u64(*)[CAPQ])(smRaw + wv3*(QW*CAPQ*8));  // 4608 B/wave
  int unit = (grp*4 + (rem - 3))*4 + wv3;                 // 0..8191
  int b  = unit / (NPTS/QW);
  int q0 = (unit % (NPTS/QW)) * QW;
  const float4* P = pts + b*NPTS;

  #pragma unroll
  for (int s = 0; s < QW*CAPQ/64; ++s){
    int f = s*64 + lane;
    smBuf[f / CAPQ][f % CAPQ] = ~0ull;
  }

  float4 qp[QW];
  #pragma unroll
  for (int i = 0; i < QW; ++i) qp[i] = P[q0 + i];

  float T[QW];
  {
    float v0 = 3.402823466e38f, v1 = 3.402823466e38f;
    #pragma unroll
    for (int j = 0; j < 16; ++j){
      float4 c = P[lane + 64*j];
      v0 = fminf(v0, d2f(qp[0], c));
      v1 = fminf(v1, d2f(qp[1], c));
    }
    float t0 = v0, t1 = v1;
    #pragma unroll
    for (int r = 0; r < 16; ++r){
      float m0 = v0, m1 = v1;
      #pragma unroll
      for (int msk = 1; msk <= 32; msk <<= 1){
        m0 = fminf(m0, __shfl_xor(m0, msk));
        m1 = fminf(m1, __shfl_xor(m1, msk));
      }
      if (v0 == m0) v0 = 3.402823466e38f;
      if (v1 == m1) v1 = 3.402823466e38f;
      t0 = m0; t1 = m1;
    }
    T[0] = t0; T[1] = t1;
  }

  float Tlo[QW], Thi[QW]; int cnt[QW];
  #pragma unroll
  for (int i = 0; i < QW; ++i){ Tlo[i] = -3.0e38f; Thi[i] = 3.0e38f; cnt[i] = 0; }
  auto step = [&](float4 c, u32 m, int i){
    float d2 = d2f(qp[i], c);
    bool pred = d2 <= T[i];
    u64 bm = __ballot(pred);
    if (bm){
      int cc = __popcll(bm);
      if (pred && cnt[i] + cc <= CAPQ){
        int pos = cnt[i] + mbcnt64(bm);
        smBuf[i][pos] = (((u64)mono32(d2)) << 32) | m;
      }
      cnt[i] += cc;
    }
  };
  bool anybad = true;
  for (int att = 0; att < 16 && anybad; ++att){
    #pragma unroll
    for (int i = 0; i < QW; ++i) cnt[i] = 0;
    float4 c0 = P[lane], c1 = P[64 + lane], c2 = P[128 + lane], c3 = P[192 + lane];
    for (int base = 0; base < NPTS; base += 256){
      float4 e0 = c0, e1 = c1, e2 = c2, e3 = c3;
      int nb = base + 256;
      if (nb < NPTS){
        c0 = P[nb       + lane];
        c1 = P[nb +  64 + lane];
        c2 = P[nb + 128 + lane];
        c3 = P[nb + 192 + lane];
      }
      #pragma unroll
      for (int i = 0; i < QW; ++i){
        step(e0, (u32)(base       + lane), i);
        step(e1, (u32)(base +  64 + lane), i);
        step(e2, (u32)(base + 128 + lane), i);
        step(e3, (u32)(base + 192 + lane), i);
      }
    }
    anybad = false;
    #pragma unroll
    for (int i = 0; i < QW; ++i){
      if (cnt[i] > CAPQ){
        Thi[i] = T[i];
        T[i] = (Tlo[i] > -3.0e38f) ? 0.5f*(Tlo[i] + Thi[i])
                                   : ((T[i] > 0.f) ? T[i]*0.5f : T[i]*2.0f - 1.0f);
        anybad = true;
      } else if (cnt[i] < 16){
        Tlo[i] = T[i];
        T[i] = 0.5f*(Tlo[i] + Thi[i]);
        anybad = true;
      }
    }
  }

  {
    int cq0 = cnt[0] < CAPQ ? cnt[0] : CAPQ;
    int cq1 = cnt[1] < CAPQ ? cnt[1] : CAPQ;
    u64 a0, a1, a2, a3, a4, b0, b1, b2, b3, b4;
    a0 = (lane       < cq0) ? smBuf[0][lane      ] : ~0ull;
    a1 = (lane +  64 < cq0) ? smBuf[0][lane +  64] : ~0ull;
    a2 = (lane + 128 < cq0) ? smBuf[0][lane + 128] : ~0ull;
    a3 = (lane + 192 < cq0) ? smBuf[0][lane + 192] : ~0ull;
    a4 = (lane + 256 < cq0) ? smBuf[0][lane + 256] : ~0ull;
    b0 = (lane       < cq1) ? smBuf[1][lane      ] : ~0ull;
    b1 = (lane +  64 < cq1) ? smBuf[1][lane +  64] : ~0ull;
    b2 = (lane + 128 < cq1) ? smBuf[1][lane + 128] : ~0ull;
    b3 = (lane + 192 < cq1) ? smBuf[1][lane + 192] : ~0ull;
    b4 = (lane + 256 < cq1) ? smBuf[1][lane + 256] : ~0ull;
    #define CE_(x,y) { if (y < x){ u64 tm_ = x; x = y; y = tm_; } }
    CE_(a0,a1) CE_(a1,a2) CE_(a2,a3) CE_(a3,a4)
    CE_(a0,a1) CE_(a1,a2) CE_(a2,a3)
    CE_(a0,a1) CE_(a1,a2)
    CE_(a0,a1)
    CE_(b0,b1) CE_(b1,b2) CE_(b2,b3) CE_(b3,b4)
    CE_(b0,b1) CE_(b1,b2) CE_(b2,b3)
    CE_(b0,b1) CE_(b1,b2)
    CE_(b0,b1)
    #undef CE_
    int nq0 = q0, nq1 = q0 + 1;
    #pragma unroll
    for (int r = 0; r < 16; ++r){
      u64 g0 = a0, g1 = b0;
      #pragma unroll
      for (int msk = 1; msk <= 32; msk <<= 1){
        u64 o0 = shfl_xor_u64(g0, msk);
        u64 o1 = shfl_xor_u64(g1, msk);
        g0 = (o0 < g0) ? o0 : g0;
        g1 = (o1 < g1) ? o1 : g1;
      }
      if (a0 == g0){ a0 = a1; a1 = a2; a2 = a3; a3 = a4; a4 = ~0ull; }
      if (b0 == g1){ b0 = b1; b1 = b2; b2 = b3; b3 = b4; b4 = ~0ull; }
      if (lane == 0){
        idxout[(b*NPTS + nq0)*16 + r] = (g0 == ~0ull) ? nq0 : (int)(g0 & (u32)(NPTS-1));
        idxout[(b*NPTS + nq1)*16 + r] = (g1 == ~0ull) ? nq1 : (int)(g1 & (u32)(NPTS-1));
      }
    }
  }
}

// ---------------- K4: fused attention, 4 points/block (verified round-16 form) ----------------
#define H2S 136
#define K4P 4
__global__ __launch_bounds__(256, 4) void k4_attn(
    const float4* pts, const float* eqT, const float* ekT, const int* idxw,
    const float* vfT, const float* wsA, const float4* wsPW1, const float* wsWE2,
    const float* pe_w2, const float* wo,
    const float* bno_g, const float* bno_b, const float* bno_m, const float* bno_v,
    float* out){
  __shared__ __align__(16) float4 smW1[128];      // 2 KB
  __shared__ __align__(16) float4 smP[4][16];     // 1 KB  r-vectors per wave
  __shared__ int   smJ[4][16];                    // 256 B neighbor indices
  __shared__ float smw[4][16][8];                 // 2 KB  weights [k][g]
  __shared__ __align__(16) float smH[4][8][H2S];  // 17.4 KB
  __shared__ __align__(16) float smOutv[4][128];  // 2 KB
  int t = threadIdx.x;
  int wv = t >> 6, lane = t & 63;
  int b  = blockIdx.x >> 11;          // NPTS/4 = 2048 blocks per batch
  int n0 = (blockIdx.x & 2047) * 4;
  if (t < 128) smW1[t] = wsPW1[t];
  __syncthreads();

  int n = n0 + wv;
  int gq = b*NPTS + n;
  int k = lane >> 2, q = lane & 3;

  // ---- phase A (wave-local): logits + softmax weights ----
  {
    float4 pn  = pts[gq];
    float4 eqa = *(const float4*)&eqT[gq*8];
    float4 eqb = *(const float4*)&eqT[gq*8+4];
    int j = idxw[gq*16 + k] & (NPTS-1);
    int gj = b*NPTS + j;
    float4 pj  = pts[gj];
    float4 eka = *(const float4*)&ekT[gj*8];
    float4 ekb = *(const float4*)&ekT[gj*8+4];
    float rx = pj.x - pn.x, ry = pj.y - pn.y, rz = pj.z - pn.z;
    if (q == 0){
      smP[wv][k] = make_float4(rx, ry, rz, 0.f);
      smJ[wv][k] = j;
    }
    // ee added ONCE after the q-lane reduction
    float ee[8] = {eka.x+eqa.x, eka.y+eqa.y, eka.z+eqa.z, eka.w+eqa.w,
                   ekb.x+eqb.x, ekb.y+eqb.y, ekb.z+eqb.z, ekb.w+eqb.w};
    float lp[8] = {0.f,0.f,0.f,0.f,0.f,0.f,0.f,0.f};
    #pragma unroll
    for (int i = 0; i < 8; ++i){
      int hb = 4*q + 16*i;
      float4 w1;
      w1 = smW1[hb+0]; float hv0 = fmaxf(fmaf(w1.x, rx, fmaf(w1.y, ry, fmaf(w1.z, rz, w1.w))), 0.f);
      w1 = smW1[hb+1]; float hv1 = fmaxf(fmaf(w1.x, rx, fmaf(w1.y, ry, fmaf(w1.z, rz, w1.w))), 0.f);
      w1 = smW1[hb+2]; float hv2 = fmaxf(fmaf(w1.x, rx, fmaf(w1.y, ry, fmaf(w1.z, rz, w1.w))), 0.f);
      w1 = smW1[hb+3]; float hv3 = fmaxf(fmaf(w1.x, rx, fmaf(w1.y, ry, fmaf(w1.z, rz, w1.w))), 0.f);
      #pragma unroll
      for (int g = 0; g < 8; ++g){
        float4 a4 = *(const float4*)&wsA[g*128 + hb];
        lp[g] = fmaf(a4.x, hv0, lp[g]);
        lp[g] = fmaf(a4.y, hv1, lp[g]);
        lp[g] = fmaf(a4.z, hv2, lp[g]);
        lp[g] = fmaf(a4.w, hv3, lp[g]);
      }
    }
    #pragma unroll
    for (int g = 0; g < 8; ++g){
      lp[g] += __shfl_xor(lp[g], 1);
      lp[g] += __shfl_xor(lp[g], 2);
      lp[g] = fmaxf(lp[g] + ee[g], 0.f);
    }
    float lo0 = 0.f, lo1 = 0.f;
    #pragma unroll
    for (int g = 0; g < 8; ++g){
      lo0 = fmaf(wsWE2[(2*q+0)*8 + g], lp[g], lo0);
      lo1 = fmaf(wsWE2[(2*q+1)*8 + g], lp[g], lo1);
    }
    float m0 = lo0, m1 = lo1;
    #pragma unroll
    for (int msk = 4; msk <= 32; msk <<= 1){
      m0 = fmaxf(m0, __shfl_xor(m0, msk));
      m1 = fmaxf(m1, __shfl_xor(m1, msk));
    }
    float e0 = __expf(lo0 - m0), e1 = __expf(lo1 - m1);
    float s0 = e0, s1 = e1;
    #pragma unroll
    for (int msk = 4; msk <= 32; msk <<= 1){
      s0 += __shfl_xor(s0, msk);
      s1 += __shfl_xor(s1, msk);
    }
    smw[wv][k][2*q+0] = e0 / s0;
    smw[wv][k][2*q+1] = e1 / s1;
  }

  // ---- phase C (wave-local): H[g][h] = sum_k w[g,k]*relu(W1[h].r_k) ----
  {
    int g3 = lane >> 3, hh = lane & 7;
    float4 H4[4];
    #pragma unroll
    for (int ii = 0; ii < 4; ++ii) H4[ii] = make_float4(0.f,0.f,0.f,0.f);
    for (int kk = 0; kk < 16; ++kk){
      float4 r4 = smP[wv][kk];
      float wg  = smw[wv][kk][g3];
      #pragma unroll
      for (int ii = 0; ii < 4; ++ii){
        int hb = 4*hh + 32*ii;
        float4 w1;
        w1 = smW1[hb+0]; float hv0 = fmaxf(fmaf(w1.x, r4.x, fmaf(w1.y, r4.y, fmaf(w1.z, r4.z, w1.w))), 0.f);
        w1 = smW1[hb+1]; float hv1 = fmaxf(fmaf(w1.x, r4.x, fmaf(w1.y, r4.y, fmaf(w1.z, r4.z, w1.w))), 0.f);
        w1 = smW1[hb+2]; float hv2 = fmaxf(fmaf(w1.x, r4.x, fmaf(w1.y, r4.y, fmaf(w1.z, r4.z, w1.w))), 0.f);
        w1 = smW1[hb+3]; float hv3 = fmaxf(fmaf(w1.x, r4.x, fmaf(w1.y, r4.y, fmaf(w1.z, r4.z, w1.w))), 0.f);
        H4[ii].x = fmaf(wg, hv0, H4[ii].x);
        H4[ii].y = fmaf(wg, hv1, H4[ii].y);
        H4[ii].z = fmaf(wg, hv2, H4[ii].z);
        H4[ii].w = fmaf(wg, hv3, H4[ii].w);
      }
    }
    #pragma unroll
    for (int ii = 0; ii < 4; ++ii)
      *(float4*)&smH[wv][g3][4*hh + 32*ii] = H4[ii];
  }
  __syncthreads();   // all waves' smH/smw/smJ visible block-wide

  // ---- phase D (block-wide, t<128): outv for all 4 points; pe_w2 rows read once ----
  if (t < 128){
    int c = t, g = c >> 4;
    float acc[4] = {0.f, 0.f, 0.f, 0.f};
    for (int i = 0; i < 32; ++i){
      float4 pw = *(const float4*)&pe_w2[c*128 + 4*i];
      #pragma unroll
      for (int pt = 0; pt < 4; ++pt){
        float4 h4 = *(const float4*)&smH[pt][g][4*i];
        acc[pt] = fmaf(pw.x, h4.x, acc[pt]);
        acc[pt] = fmaf(pw.y, h4.y, acc[pt]);
        acc[pt] = fmaf(pw.z, h4.z, acc[pt]);
        acc[pt] = fmaf(pw.w, h4.w, acc[pt]);
      }
    }
    #pragma unroll
    for (int pt = 0; pt < 4; ++pt){
      #pragma unroll
      for (int kk = 0; kk < 16; ++kk){
        int jj = smJ[pt][kk];
        float wgk = smw[pt][kk][g];
        acc[pt] = fmaf(wgk, vfT[((size_t)b*NPTS + jj)*CH + c], acc[pt]);
      }
      smOutv[pt][c] = acc[pt];
    }
  }
  __syncthreads();

  // ---- phase E (t<128): out[o][n0..n0+3] = bno(wo @ outv), float4 store ----
  if (t < 128){
    int o = t;
    float so = bno_g[o] / sqrtf(bno_v[o] + EPSN);
    float bo = bno_b[o] - bno_m[o] * so;
    float fa[4] = {0.f, 0.f, 0.f, 0.f};
    for (int i = 0; i < 32; ++i){
      float4 pw = *(const float4*)&wo[o*128 + 4*i];
      #pragma unroll
      for (int pt = 0; pt < 4; ++pt){
        float4 h4 = *(const float4*)&smOutv[pt][4*i];
        fa[pt] = fmaf(pw.x, h4.x, fa[pt]);
        fa[pt] = fmaf(pw.y, h4.y, fa[pt]);
        fa[pt] = fmaf(pw.z, h4.z, fa[pt]);
        fa[pt] = fmaf(pw.w, h4.w, fa[pt]);
      }
    }
    float4 st;
    st.x = fmaf(so, fa[0], bo);
    st.y = fmaf(so, fa[1], bo);
    st.z = fmaf(so, fa[2], bo);
    st.w = fmaf(so, fa[3], bo);
    *(float4*)&out[((size_t)b*CH + o)*NPTS + n0] = st;
  }
}

extern "C" void kernel_launch(void* const* d_in, const int* in_sizes, int n_in,
                              void* d_out, int out_size, void* d_ws, size_t ws_size,
                              hipStream_t stream){
  const float* x     = (const float*)d_in[0];
  const float* xyz   = (const float*)d_in[1];
  const float* wq    = (const float*)d_in[2];
  const float* bnq_g = (const float*)d_in[3];
  const float* bnq_b = (const float*)d_in[4];
  const float* bnq_m = (const float*)d_in[5];
  const float* bnq_v = (const float*)d_in[6];
  const float* wk    = (const float*)d_in[7];
  const float* bnk_g = (const float*)d_in[8];
  const float* bnk_b = (const float*)d_in[9];
  const float* bnk_m = (const float*)d_in[10];
  const float* bnk_v = (const float*)d_in[11];
  const float* wv    = (const float*)d_in[12];
  const float* pe_w1 = (const float*)d_in[13];
  const float* pe_g  = (const float*)d_in[14];
  const float* pe_b  = (const float*)d_in[15];
  const float* pe_m  = (const float*)d_in[16];
  const float* pe_v  = (const float*)d_in[17];
  const float* pe_w2 = (const float*)d_in[18];
  const float* we_w1 = (const float*)d_in[19];
  const float* we_g  = (const float*)d_in[20];
  const float* we_b  = (const float*)d_in[21];
  const float* we_m  = (const float*)d_in[22];
  const float* we_v  = (const float*)d_in[23];
  const float* we_w2 = (const float*)d_in[24];
  const float* wo    = (const float*)d_in[25];
  const float* bno_g = (const float*)d_in[26];
  const float* bno_b = (const float*)d_in[27];
  const float* bno_m = (const float*)d_in[28];
  const float* bno_v = (const float*)d_in[29];

  char* ws = (char*)d_ws;
  float*  wsA   = (float*)(ws + WS_A);
  float4* wsPW1 = (float4*)(ws + WS_PW1);
  float*  wsWE2 = (float*)(ws + WS_WE2);
  float4* pts   = (float4*)(ws + WS_PTS);
  float*  eqT   = (float*)(ws + WS_EQ);
  float*  ekT   = (float*)(ws + WS_EK);
  int*    idxw  = (int*)(ws + WS_IDX);
  float*  vfT   = (float*)(ws + WS_VFT);
  float*  outp  = (float*)d_out;

  k0_precomp<<<dim3(1), dim3(256), 0, stream>>>(we_w1, pe_w2, pe_w1, we_g, we_v,
                                                pe_g, pe_b, pe_m, pe_v, we_w2,
                                                wsA, wsPW1, wsWE2);
  k1_pts<<<dim3(64), dim3(256), 0, stream>>>(xyz, pts);
  // 3584 blocks = 512 groups x (3 k2-role + 4 k3-role)
  k23_fused<<<dim3(3584), dim3(256), K23_LDS, stream>>>(x, wq, wk, wv,
                                               bnq_g, bnq_b, bnq_m, bnq_v,
                                               bnk_g, bnk_b, bnk_m, bnk_v,
                                               we_w1, we_g, we_b, we_m, we_v,
                                               eqT, ekT, vfT, pts, idxw);
  k4_attn<<<dim3(BATCH*(NPTS/K4P)), dim3(256), 0, stream>>>(pts, eqT, ekT, idxw, vfT,
                                                wsA, wsPW1, wsWE2, pe_w2, wo,
                                                bno_g, bno_b, bno_m, bno_v, outp);
}